// Round 1
// baseline (679.341 us; speedup 1.0000x reference)
//
#include <hip/hip_runtime.h>
#include <stdint.h>

#define BB 8
#define CC 64
#define HW 4096          // H*W
#define NTOK 32768       // B*H*W
#define KCB 8192
#define TOK_TILE 128
#define CODE_TILE 128
#define KSPLIT 4

// ---------------------------------------------------------------------------
// Kernel 1: pre_quant conv (1x1 channel mix): ze[n][o] = sum_c z[b,c,hw]*W[o,c] + b[o]
// also zz[n] = ||ze_n||^2. ze stored token-major [N,64] for the distance pass.
// ---------------------------------------------------------------------------
__global__ __launch_bounds__(256) void preconv_kernel(
    const float* __restrict__ z, const float* __restrict__ pre_w,
    const float* __restrict__ pre_b, float* __restrict__ ze, float* __restrict__ zz)
{
    // transposed weights: wt[c*64+o] = W[o*64+c]  (so inner o-loop reads are contiguous b128)
    __shared__ __attribute__((aligned(16))) float wt[64 * 64];
    __shared__ float bls[64];
    const int t = threadIdx.x;
    for (int i = t; i < 64 * 64; i += 256) {
        int o = i >> 6, c = i & 63;
        wt[c * 64 + o] = pre_w[i];
    }
    if (t < 64) bls[t] = pre_b[t];
    __syncthreads();

    const int n  = blockIdx.x * 256 + t;
    const int b  = n >> 12;      // / 4096
    const int hw = n & 4095;
    const float* zp = z + (size_t)b * (64 * HW) + hw;

    float acc[64];
    #pragma unroll
    for (int o = 0; o < 64; ++o) acc[o] = 0.f;

    for (int c = 0; c < 64; ++c) {
        float v = zp[(size_t)c * HW];   // coalesced across lanes
        #pragma unroll
        for (int og = 0; og < 16; ++og) {
            float4 w4 = *(const float4*)(wt + c * 64 + og * 4);  // wave-uniform broadcast
            acc[og*4+0] = fmaf(v, w4.x, acc[og*4+0]);
            acc[og*4+1] = fmaf(v, w4.y, acc[og*4+1]);
            acc[og*4+2] = fmaf(v, w4.z, acc[og*4+2]);
            acc[og*4+3] = fmaf(v, w4.w, acc[og*4+3]);
        }
    }

    float s = 0.f;
    #pragma unroll
    for (int o = 0; o < 64; ++o) {
        float v = acc[o] + bls[o];
        acc[o] = v;
        s += v * v;
    }
    float4* zr4 = (float4*)(ze + (size_t)n * 64);
    #pragma unroll
    for (int j = 0; j < 16; ++j)
        zr4[j] = make_float4(acc[4*j], acc[4*j+1], acc[4*j+2], acc[4*j+3]);
    zz[n] = s;
}

// ---------------------------------------------------------------------------
// Kernel 2: ee[k] = ||emb_k||^2
// ---------------------------------------------------------------------------
__global__ __launch_bounds__(256) void embnorm_kernel(
    const float* __restrict__ emb, float* __restrict__ ee)
{
    const int k = blockIdx.x * 256 + threadIdx.x;
    const float4* er = (const float4*)(emb + (size_t)k * 64);
    float s = 0.f;
    #pragma unroll
    for (int j = 0; j < 16; ++j) {
        float4 v = er[j];
        s += v.x*v.x + v.y*v.y + v.z*v.z + v.w*v.w;
    }
    ee[k] = s;
}

// ---------------------------------------------------------------------------
// Kernel 3: init packed argmin keys to +inf
// ---------------------------------------------------------------------------
__global__ __launch_bounds__(256) void initkeys_kernel(unsigned long long* __restrict__ keys)
{
    keys[blockIdx.x * 256 + threadIdx.x] = 0xFFFFFFFFFFFFFFFFULL;
}

// ---------------------------------------------------------------------------
// Kernel 4: distance GEMM + argmin.
// Block tile 128 tokens x 128 codes; thread tile 8x8 (16x16 thread grid).
// LDS c-major so inner reads are b128 with broadcast / free 2-way patterns.
// d = zz - 2*dot + ee, packed key (d_bits<<32)|idx -> u64 atomicMin (exact
// first-occurrence argmin semantics, deterministic).
// ---------------------------------------------------------------------------
__global__ __launch_bounds__(256) void dist_kernel(
    const float* __restrict__ ze, const float* __restrict__ zz,
    const float* __restrict__ emb, const float* __restrict__ ee,
    unsigned long long* __restrict__ keys)
{
    __shared__ __attribute__((aligned(16))) float a_lds[64 * TOK_TILE];   // [c][token] 32KB
    __shared__ __attribute__((aligned(16))) float b_lds[64 * CODE_TILE];  // [c][code]  32KB
    __shared__ float ee_lds[CODE_TILE];
    __shared__ float zz_lds[TOK_TILE];

    const int t  = threadIdx.x;
    const int tx = t & 15, ty = t >> 4;
    const int tok0   = blockIdx.x * TOK_TILE;
    const int kbase0 = blockIdx.y * (KCB / KSPLIT);

    // ---- stage A (once per block), transposed to c-major ----
    {
        int tt = t >> 1, hh = t & 1;
        const float4* src = (const float4*)(ze + (size_t)(tok0 + tt) * 64 + hh * 32);
        #pragma unroll
        for (int j = 0; j < 8; ++j) {
            float4 v = src[j];
            int c = hh * 32 + j * 4;
            a_lds[(c+0) * TOK_TILE + tt] = v.x;
            a_lds[(c+1) * TOK_TILE + tt] = v.y;
            a_lds[(c+2) * TOK_TILE + tt] = v.z;
            a_lds[(c+3) * TOK_TILE + tt] = v.w;
        }
        if (t < TOK_TILE) zz_lds[t] = zz[tok0 + t];
    }

    unsigned long long best[8];
    #pragma unroll
    for (int i = 0; i < 8; ++i) best[i] = 0xFFFFFFFFFFFFFFFFULL;

    __syncthreads();
    float zzr[8];
    #pragma unroll
    for (int i = 0; i < 8; ++i) zzr[i] = zz_lds[ty * 8 + i];

    for (int kt = 0; kt < (KCB / KSPLIT) / CODE_TILE; ++kt) {
        const int kb = kbase0 + kt * CODE_TILE;
        __syncthreads();   // previous tile fully consumed
        // ---- stage B tile ----
        {
            int ct = t >> 1, hh = t & 1;
            const float4* src = (const float4*)(emb + (size_t)(kb + ct) * 64 + hh * 32);
            #pragma unroll
            for (int j = 0; j < 8; ++j) {
                float4 v = src[j];
                int c = hh * 32 + j * 4;
                b_lds[(c+0) * CODE_TILE + ct] = v.x;
                b_lds[(c+1) * CODE_TILE + ct] = v.y;
                b_lds[(c+2) * CODE_TILE + ct] = v.z;
                b_lds[(c+3) * CODE_TILE + ct] = v.w;
            }
            if (t < CODE_TILE) ee_lds[t] = ee[kb + t];
        }
        __syncthreads();

        float acc[8][8];
        #pragma unroll
        for (int i = 0; i < 8; ++i)
            #pragma unroll
            for (int j = 0; j < 8; ++j) acc[i][j] = 0.f;

        #pragma unroll 8
        for (int c = 0; c < 64; ++c) {
            const float4 a0 = *(const float4*)(a_lds + c * TOK_TILE + ty * 8);
            const float4 a1 = *(const float4*)(a_lds + c * TOK_TILE + ty * 8 + 4);
            const float4 b0 = *(const float4*)(b_lds + c * CODE_TILE + tx * 8);
            const float4 b1 = *(const float4*)(b_lds + c * CODE_TILE + tx * 8 + 4);
            float av[8] = {a0.x, a0.y, a0.z, a0.w, a1.x, a1.y, a1.z, a1.w};
            float bv[8] = {b0.x, b0.y, b0.z, b0.w, b1.x, b1.y, b1.z, b1.w};
            #pragma unroll
            for (int i = 0; i < 8; ++i)
                #pragma unroll
                for (int j = 0; j < 8; ++j)
                    acc[i][j] = fmaf(av[i], bv[j], acc[i][j]);
        }

        #pragma unroll
        for (int i = 0; i < 8; ++i) {
            #pragma unroll
            for (int j = 0; j < 8; ++j) {
                const int code = kb + tx * 8 + j;
                float d = fmaf(-2.f, acc[i][j], zzr[i] + ee_lds[tx * 8 + j]);
                unsigned long long key =
                    ((unsigned long long)__float_as_uint(d) << 32) | (unsigned)code;
                if (key < best[i]) best[i] = key;
            }
        }
    }

    // ---- reduce across the 16 tx-columns per token (reuse a_lds, stride 17 to
    // break the all-lanes-same-bank pattern), then one atomicMin per token ----
    __syncthreads();
    unsigned long long* kred = (unsigned long long*)a_lds;  // 128*17*8 = 17.4KB < 32KB
    #pragma unroll
    for (int i = 0; i < 8; ++i)
        kred[(ty * 8 + i) * 17 + tx] = best[i];
    __syncthreads();
    if (t < TOK_TILE) {
        unsigned long long m = kred[t * 17];
        #pragma unroll
        for (int j = 1; j < 16; ++j) {
            unsigned long long v = kred[t * 17 + j];
            if (v < m) m = v;
        }
        atomicMin(&keys[tok0 + t], m);
    }
}

// ---------------------------------------------------------------------------
// Kernel 5: gather q = emb[idx], out = q @ post_w^T + post_b (quant fwd == q),
// per-block partial of sum((ze-q)^2).
// ---------------------------------------------------------------------------
__global__ __launch_bounds__(256) void gather_kernel(
    const float* __restrict__ emb, const unsigned long long* __restrict__ keys,
    const float* __restrict__ ze, const float* __restrict__ post_w,
    const float* __restrict__ post_b, float* __restrict__ out,
    float* __restrict__ lossp)
{
    __shared__ __attribute__((aligned(16))) float wt[64 * 64];  // transposed post_w
    __shared__ float bls[64];
    __shared__ float red[4];
    const int t = threadIdx.x;
    for (int i = t; i < 64 * 64; i += 256) {
        int o = i >> 6, c = i & 63;
        wt[c * 64 + o] = post_w[i];
    }
    if (t < 64) bls[t] = post_b[t];
    __syncthreads();

    const int n  = blockIdx.x * 256 + t;
    const int b  = n >> 12;
    const int hw = n & 4095;
    const int idx = (int)(keys[n] & 0xFFFFFFFFULL);

    const float4* qr = (const float4*)(emb + (size_t)idx * 64);
    const float4* zr = (const float4*)(ze + (size_t)n * 64);

    float acc[64];
    #pragma unroll
    for (int o = 0; o < 64; ++o) acc[o] = 0.f;

    float l = 0.f;
    #pragma unroll
    for (int j = 0; j < 16; ++j) {
        float4 qv = qr[j];
        float4 zv = zr[j];
        float d0 = zv.x - qv.x, d1 = zv.y - qv.y, d2 = zv.z - qv.z, d3 = zv.w - qv.w;
        l += d0*d0 + d1*d1 + d2*d2 + d3*d3;
        float qc[4] = {qv.x, qv.y, qv.z, qv.w};
        #pragma unroll
        for (int cc = 0; cc < 4; ++cc) {
            const int c = j * 4 + cc;
            #pragma unroll
            for (int og = 0; og < 16; ++og) {
                float4 w4 = *(const float4*)(wt + c * 64 + og * 4);
                acc[og*4+0] = fmaf(qc[cc], w4.x, acc[og*4+0]);
                acc[og*4+1] = fmaf(qc[cc], w4.y, acc[og*4+1]);
                acc[og*4+2] = fmaf(qc[cc], w4.z, acc[og*4+2]);
                acc[og*4+3] = fmaf(qc[cc], w4.w, acc[og*4+3]);
            }
        }
    }

    float* op = out + (size_t)b * (64 * HW) + hw;
    #pragma unroll
    for (int o = 0; o < 64; ++o)
        op[(size_t)o * HW] = acc[o] + bls[o];   // coalesced per-o across lanes

    // block-reduce loss partial
    #pragma unroll
    for (int off = 32; off > 0; off >>= 1) l += __shfl_down(l, off, 64);
    if ((t & 63) == 0) red[t >> 6] = l;
    __syncthreads();
    if (t == 0) lossp[blockIdx.x] = red[0] + red[1] + red[2] + red[3];
}

// ---------------------------------------------------------------------------
// Kernel 6: final loss reduce: loss = 1.25 * sum / (B*C*H*W)
// ---------------------------------------------------------------------------
__global__ void lossred_kernel(const float* __restrict__ lossp, float* __restrict__ loss_out)
{
    __shared__ double sd[128];
    const int t = threadIdx.x;
    sd[t] = (double)lossp[t];
    __syncthreads();
    for (int off = 64; off > 0; off >>= 1) {
        if (t < off) sd[t] += sd[t + off];
        __syncthreads();
    }
    if (t == 0)
        loss_out[0] = (float)(1.25 * sd[0] / (double)(NTOK * 64));
}

// ---------------------------------------------------------------------------
extern "C" void kernel_launch(void* const* d_in, const int* in_sizes, int n_in,
                              void* d_out, int out_size, void* d_ws, size_t ws_size,
                              hipStream_t stream)
{
    const float* z      = (const float*)d_in[0];
    const float* pre_w  = (const float*)d_in[1];
    const float* pre_b  = (const float*)d_in[2];
    const float* emb    = (const float*)d_in[3];
    const float* post_w = (const float*)d_in[4];
    const float* post_b = (const float*)d_in[5];
    float* outp = (float*)d_out;                 // [8,64,64,64] then loss scalar

    // workspace layout (all within ~8.9 MB)
    float* ze = (float*)d_ws;                          // 32768*64 floats
    float* zz = ze + (size_t)NTOK * 64;                // 32768
    float* ee = zz + NTOK;                             // 8192
    unsigned long long* keys = (unsigned long long*)(ee + KCB);  // 32768 u64, 8B-aligned
    float* lossp = (float*)(keys + NTOK);              // 128 floats

    preconv_kernel<<<NTOK / 256, 256, 0, stream>>>(z, pre_w, pre_b, ze, zz);
    embnorm_kernel<<<KCB / 256, 256, 0, stream>>>(emb, ee);
    initkeys_kernel<<<NTOK / 256, 256, 0, stream>>>(keys);
    dist_kernel<<<dim3(NTOK / TOK_TILE, KSPLIT), 256, 0, stream>>>(ze, zz, emb, ee, keys);
    gather_kernel<<<NTOK / 256, 256, 0, stream>>>(emb, keys, ze, post_w, post_b, outp, lossp);
    lossred_kernel<<<1, 128, 0, stream>>>(lossp, outp + (size_t)NTOK * 64);
}

// Round 2
// 483.891 us; speedup vs baseline: 1.4039x; 1.4039x over previous
//
#include <hip/hip_runtime.h>
#include <stdint.h>

#define HW 4096
#define NTOK 32768
#define KCB 8192
#define MARGIN 0.0625f

typedef __bf16 bf16x8 __attribute__((ext_vector_type(8)));
typedef float f32x16 __attribute__((ext_vector_type(16)));
typedef unsigned int uint;
typedef unsigned short u16;
typedef unsigned long long u64;

static __device__ inline u16 f2bf(float f) {
    uint u = __float_as_uint(f);
    return (u16)((u + 0x7FFFu + ((u >> 16) & 1u)) >> 16);   // RNE
}
static __device__ inline float bf2f(u16 h) {
    return __uint_as_float(((uint)h) << 16);
}

// ---------------------------------------------------------------------------
// embprep: ee[k] = ||emb_k||^2; embq[k] = 128 bf16 (64 hi then 64 lo) stored in
// 16B columns XOR-swizzled by (k&7) so LDS ds_read_b128 is bank-conflict-free.
// Also zeroes the flag counter.
// ---------------------------------------------------------------------------
__global__ __launch_bounds__(256) void embprep_kernel(
    const float* __restrict__ emb, u16* __restrict__ embq,
    float* __restrict__ ee, int* __restrict__ flagcnt)
{
    const int k = blockIdx.x * 256 + threadIdx.x;
    const float4* er = (const float4*)(emb + (size_t)k * 64);
    float vals[64]; float s = 0.f;
    #pragma unroll
    for (int j = 0; j < 16; ++j) {
        float4 v = er[j];
        vals[4*j+0] = v.x; vals[4*j+1] = v.y; vals[4*j+2] = v.z; vals[4*j+3] = v.w;
        s += v.x*v.x + v.y*v.y + v.z*v.z + v.w*v.w;
    }
    ee[k] = s;
    u16 hb[64], lb[64];
    #pragma unroll
    for (int c = 0; c < 64; ++c) {
        hb[c] = f2bf(vals[c]);
        lb[c] = f2bf(vals[c] - bf2f(hb[c]));
    }
    uint4* out = (uint4*)(embq + (size_t)k * 128);
    const int sw = k & 7;
    #pragma unroll
    for (int cl = 0; cl < 8; ++cl) {           // hi columns
        uint4 u;
        u.x = (uint)hb[cl*8+0] | ((uint)hb[cl*8+1] << 16);
        u.y = (uint)hb[cl*8+2] | ((uint)hb[cl*8+3] << 16);
        u.z = (uint)hb[cl*8+4] | ((uint)hb[cl*8+5] << 16);
        u.w = (uint)hb[cl*8+6] | ((uint)hb[cl*8+7] << 16);
        out[cl ^ sw] = u;
    }
    #pragma unroll
    for (int cl = 8; cl < 16; ++cl) {          // lo columns
        const int b = (cl - 8) * 8;
        uint4 u;
        u.x = (uint)lb[b+0] | ((uint)lb[b+1] << 16);
        u.y = (uint)lb[b+2] | ((uint)lb[b+3] << 16);
        u.z = (uint)lb[b+4] | ((uint)lb[b+5] << 16);
        u.w = (uint)lb[b+6] | ((uint)lb[b+7] << 16);
        out[cl ^ sw] = u;
    }
    if (k == 0) *flagcnt = 0;
}

// ---------------------------------------------------------------------------
// preconv: ze = z @ pre_w^T + pre_b (1x1 conv); outputs zz = ||ze||^2 and
// zq[n] = 128 bf16 row (64 hi, 64 lo), plain layout (A side reads global).
// ---------------------------------------------------------------------------
__global__ __launch_bounds__(256) void preconv_kernel(
    const float* __restrict__ z, const float* __restrict__ pre_w,
    const float* __restrict__ pre_b, u16* __restrict__ zq, float* __restrict__ zz)
{
    __shared__ __attribute__((aligned(16))) float wt[64 * 64];
    __shared__ float bls[64];
    const int t = threadIdx.x;
    for (int i = t; i < 64 * 64; i += 256) {
        int o = i >> 6, c = i & 63;
        wt[c * 64 + o] = pre_w[i];
    }
    if (t < 64) bls[t] = pre_b[t];
    __syncthreads();

    const int n  = blockIdx.x * 256 + t;
    const int b  = n >> 12;
    const int hw = n & 4095;
    const float* zp = z + (size_t)b * (64 * HW) + hw;

    float acc[64];
    #pragma unroll
    for (int o = 0; o < 64; ++o) acc[o] = 0.f;

    for (int c = 0; c < 64; ++c) {
        float v = zp[(size_t)c * HW];
        #pragma unroll
        for (int og = 0; og < 16; ++og) {
            float4 w4 = *(const float4*)(wt + c * 64 + og * 4);
            acc[og*4+0] = fmaf(v, w4.x, acc[og*4+0]);
            acc[og*4+1] = fmaf(v, w4.y, acc[og*4+1]);
            acc[og*4+2] = fmaf(v, w4.z, acc[og*4+2]);
            acc[og*4+3] = fmaf(v, w4.w, acc[og*4+3]);
        }
    }

    float s = 0.f;
    #pragma unroll
    for (int o = 0; o < 64; ++o) {
        float v = acc[o] + bls[o];
        acc[o] = v;
        s += v * v;
    }
    zz[n] = s;

    uint uh[32], ul[32];
    #pragma unroll
    for (int j = 0; j < 32; ++j) {
        float v0 = acc[2*j], v1 = acc[2*j+1];
        u16 h0 = f2bf(v0), h1 = f2bf(v1);
        u16 l0 = f2bf(v0 - bf2f(h0)), l1 = f2bf(v1 - bf2f(h1));
        uh[j] = (uint)h0 | ((uint)h1 << 16);
        ul[j] = (uint)l0 | ((uint)l1 << 16);
    }
    uint4* zr = (uint4*)(zq + (size_t)n * 128);
    #pragma unroll
    for (int j = 0; j < 8; ++j) {
        zr[j]     = *(uint4*)&uh[4*j];
        zr[8 + j] = *(uint4*)&ul[4*j];
    }
}

// ---------------------------------------------------------------------------
// dist: split-bf16 MFMA distance pass. 256 blocks (1/CU) x 4 waves.
// Wave w owns 32 tokens (tg..tg+31); each chunk = 128 codes staged to LDS via
// global_load_lds (pre-swizzled layout), double-buffered.
// Per token: running best/second-best of d' = ee - 2*dot (zz dropped: constant
// per token). Tokens with (second-best)-(best) < MARGIN are flagged for the
// exact fp32 cleanup pass.
// ---------------------------------------------------------------------------
__global__ __launch_bounds__(256, 1) void dist_kernel(
    const u16* __restrict__ zq, const u16* __restrict__ embq,
    const float* __restrict__ ee, uint* __restrict__ bestidx,
    int* __restrict__ flagcnt, int* __restrict__ flaglist)
{
    __shared__ __attribute__((aligned(16))) char smem[65536];

    const int t    = threadIdx.x;
    const int w    = t >> 6;
    const int l    = t & 63;
    const int col  = l & 31;
    const int half = l >> 5;
    const int tok0 = blockIdx.x * 128;
    const int tg   = tok0 + w * 32;

    // A fragments in registers for the whole kernel: lane holds
    // A[m=col][k = s*16 + half*8 + j], 8 contiguous bf16 per (s, hi/lo).
    bf16x8 afh[4], afl[4];
    {
        const u16* zrow = zq + (size_t)(tg + col) * 128;
        #pragma unroll
        for (int s = 0; s < 4; ++s) {
            afh[s] = *(const bf16x8*)(zrow + s*16 + half*8);
            afl[s] = *(const bf16x8*)(zrow + 64 + s*16 + half*8);
        }
    }

    float bval[16], sval[16]; uint bidx[16];
    #pragma unroll
    for (int r = 0; r < 16; ++r) { bval[r] = 3.0e38f; sval[r] = 3.0e38f; bidx[r] = 0; }

    // stage chunk 0
    {
        const char* g = (const char*)embq;
        #pragma unroll
        for (int i = 0; i < 8; ++i) {
            int off = i * 4096 + t * 16;
            __builtin_amdgcn_global_load_lds(
                (const __attribute__((address_space(1))) void*)(g + off),
                (__attribute__((address_space(3))) void*)(smem + off), 16, 0, 0);
        }
    }

    for (int kt = 0; kt < 64; ++kt) {
        __syncthreads();                       // drains chunk kt's loads
        if (kt + 1 < 64) {                     // issue next chunk into other buffer
            const char* g = (const char*)embq + (size_t)(kt + 1) * 32768;
            char* ld = smem + ((kt + 1) & 1) * 32768;
            #pragma unroll
            for (int i = 0; i < 8; ++i) {
                int off = i * 4096 + t * 16;
                __builtin_amdgcn_global_load_lds(
                    (const __attribute__((address_space(1))) void*)(g + off),
                    (__attribute__((address_space(3))) void*)(ld + off), 16, 0, 0);
            }
        }
        const char* buf = smem + (kt & 1) * 32768;
        const int kc = kt * 128;

        float eev[4];
        #pragma unroll
        for (int ct = 0; ct < 4; ++ct) eev[ct] = ee[kc + ct*32 + col];

        f32x16 acc[4];
        #pragma unroll
        for (int ct = 0; ct < 4; ++ct)
            #pragma unroll
            for (int r = 0; r < 16; ++r) acc[ct][r] = 0.f;

        #pragma unroll
        for (int s = 0; s < 4; ++s) {
            bf16x8 bh[4], bl[4];
            #pragma unroll
            for (int ct = 0; ct < 4; ++ct) {
                const int n = ct*32 + col;
                const int clh = s*2 + half;        // hi 16B-column
                const int cll = 8 + s*2 + half;    // lo 16B-column
                const char* rowp = buf + n * 256;
                bh[ct] = *(const bf16x8*)(rowp + ((clh ^ (n & 7)) << 4));
                bl[ct] = *(const bf16x8*)(rowp + ((cll ^ (n & 7)) << 4));
            }
            #pragma unroll
            for (int ct = 0; ct < 4; ++ct)
                acc[ct] = __builtin_amdgcn_mfma_f32_32x32x16_bf16(afh[s], bh[ct], acc[ct], 0, 0, 0);
            #pragma unroll
            for (int ct = 0; ct < 4; ++ct)
                acc[ct] = __builtin_amdgcn_mfma_f32_32x32x16_bf16(afh[s], bl[ct], acc[ct], 0, 0, 0);
            #pragma unroll
            for (int ct = 0; ct < 4; ++ct)
                acc[ct] = __builtin_amdgcn_mfma_f32_32x32x16_bf16(afl[s], bh[ct], acc[ct], 0, 0, 0);
        }

        // epilogue: d' = ee - 2*dot; top-2 tracking per token slot
        #pragma unroll
        for (int ct = 0; ct < 4; ++ct) {
            const uint code = (uint)(kc + ct*32 + col);
            #pragma unroll
            for (int r = 0; r < 16; ++r) {
                float d = fmaf(-2.0f, acc[ct][r], eev[ct]);
                float nb = fminf(bval[r], d);
                sval[r]  = fminf(sval[r], fmaxf(bval[r], d));
                bidx[r]  = (d < bval[r]) ? code : bidx[r];
                bval[r]  = nb;
            }
        }
    }

    // cross-lane/wave merge: C/D row = (r&3) + 8*(r>>2) + 4*half (verified map)
    __syncthreads();
    float* mbv = (float*)smem;                 // [4][32][32]
    float* msv = mbv + 4096;
    uint*  mbi = (uint*)(msv + 4096);
    #pragma unroll
    for (int r = 0; r < 16; ++r) {
        int tw = (r & 3) + 8 * (r >> 2) + 4 * half;
        int o = (w * 32 + tw) * 32 + col;
        mbv[o] = bval[r]; msv[o] = sval[r]; mbi[o] = bidx[r];
    }
    __syncthreads();
    if (t < 128) {
        int o = t * 32;
        float bv = mbv[o], sv = msv[o]; uint bi = mbi[o];
        for (int j = 1; j < 32; ++j) {
            float v = mbv[o + j], s2 = msv[o + j]; uint i2 = mbi[o + j];
            float ns = fminf(fmaxf(bv, v), fminf(sv, s2));
            if (v < bv) bi = i2;
            bv = fminf(bv, v);
            sv = ns;
        }
        const int tok = tok0 + t;
        bestidx[tok] = bi;
        if (sv - bv < MARGIN) {
            int pos = atomicAdd(flagcnt, 1);
            flaglist[pos] = tok;
        }
    }
}

// ---------------------------------------------------------------------------
// cleanup: exact fp32 rescan (packed-key argmin, first-index tiebreak) for
// flagged near-tie tokens. 4 tokens share one emb stream per block.
// ---------------------------------------------------------------------------
__global__ __launch_bounds__(256) void cleanup_kernel(
    const u16* __restrict__ zq, const float* __restrict__ zz,
    const float* __restrict__ emb, const float* __restrict__ ee,
    const int* __restrict__ flagcnt, const int* __restrict__ flaglist,
    uint* __restrict__ bestidx)
{
    const int cnt = *flagcnt;
    __shared__ __attribute__((aligned(16))) float zf[4][64];
    __shared__ float zzs[4];
    __shared__ u64 bkey[4];
    __shared__ int toks[4];
    const int t = threadIdx.x;

    for (int base = blockIdx.x * 4; base < cnt; base += 256) {
        const int nt = min(4, cnt - base);
        if (t < 4) {
            bkey[t] = ~0ull;
            toks[t] = (t < nt) ? flaglist[base + t] : 0;
        }
        __syncthreads();
        {
            const int slot = t >> 6, c = t & 63;
            if (slot < 4) {
                if (slot < nt) {
                    const u16* zrow = zq + (size_t)toks[slot] * 128;
                    zf[slot][c] = bf2f(zrow[c]) + bf2f(zrow[64 + c]);
                    if (c == 0) zzs[slot] = zz[toks[slot]];
                } else {
                    zf[slot][c] = 0.f;
                    if (c == 0) zzs[slot] = 0.f;
                }
            }
        }
        __syncthreads();

        u64 loc[4] = {~0ull, ~0ull, ~0ull, ~0ull};
        for (int k = t; k < KCB; k += 256) {
            const float4* er = (const float4*)(emb + (size_t)k * 64);
            float d0 = 0.f, d1 = 0.f, d2 = 0.f, d3 = 0.f;
            #pragma unroll 4
            for (int j = 0; j < 16; ++j) {
                float4 e = er[j];
                float4 z0 = *(const float4*)&zf[0][4*j];
                float4 z1 = *(const float4*)&zf[1][4*j];
                float4 z2 = *(const float4*)&zf[2][4*j];
                float4 z3 = *(const float4*)&zf[3][4*j];
                d0 = fmaf(e.x, z0.x, fmaf(e.y, z0.y, fmaf(e.z, z0.z, fmaf(e.w, z0.w, d0))));
                d1 = fmaf(e.x, z1.x, fmaf(e.y, z1.y, fmaf(e.z, z1.z, fmaf(e.w, z1.w, d1))));
                d2 = fmaf(e.x, z2.x, fmaf(e.y, z2.y, fmaf(e.z, z2.z, fmaf(e.w, z2.w, d2))));
                d3 = fmaf(e.x, z3.x, fmaf(e.y, z3.y, fmaf(e.z, z3.z, fmaf(e.w, z3.w, d3))));
            }
            const float eek = ee[k];
            float dd0 = fmaf(-2.f, d0, zzs[0] + eek);
            float dd1 = fmaf(-2.f, d1, zzs[1] + eek);
            float dd2 = fmaf(-2.f, d2, zzs[2] + eek);
            float dd3 = fmaf(-2.f, d3, zzs[3] + eek);
            u64 k0 = ((u64)__float_as_uint(dd0) << 32) | (uint)k;
            u64 k1 = ((u64)__float_as_uint(dd1) << 32) | (uint)k;
            u64 k2 = ((u64)__float_as_uint(dd2) << 32) | (uint)k;
            u64 k3 = ((u64)__float_as_uint(dd3) << 32) | (uint)k;
            if (k0 < loc[0]) loc[0] = k0;
            if (k1 < loc[1]) loc[1] = k1;
            if (k2 < loc[2]) loc[2] = k2;
            if (k3 < loc[3]) loc[3] = k3;
        }
        #pragma unroll
        for (int s = 0; s < 4; ++s)
            if (s < nt) atomicMin(&bkey[s], loc[s]);
        __syncthreads();
        if (t < nt) bestidx[toks[t]] = (uint)(bkey[t] & 0xFFFFFFFFull);
        __syncthreads();
    }
}

// ---------------------------------------------------------------------------
// gather: q = emb[idx]; out = q @ post_w^T + post_b; loss partials from
// (ze - q)^2 with ze reconstructed as hi+lo (error ~2^-18, harmless).
// ---------------------------------------------------------------------------
__global__ __launch_bounds__(256) void gather_kernel(
    const float* __restrict__ emb, const uint* __restrict__ bestidx,
    const u16* __restrict__ zq, const float* __restrict__ post_w,
    const float* __restrict__ post_b, float* __restrict__ out,
    float* __restrict__ lossp)
{
    __shared__ __attribute__((aligned(16))) float wt[64 * 64];
    __shared__ float bls[64];
    __shared__ float red[4];
    const int t = threadIdx.x;
    for (int i = t; i < 64 * 64; i += 256) {
        int o = i >> 6, c = i & 63;
        wt[c * 64 + o] = post_w[i];
    }
    if (t < 64) bls[t] = post_b[t];
    __syncthreads();

    const int n  = blockIdx.x * 256 + t;
    const int b  = n >> 12;
    const int hw = n & 4095;
    const int idx = (int)bestidx[n];

    const float4* qr = (const float4*)(emb + (size_t)idx * 64);
    const uint4*  zr = (const uint4*)(zq + (size_t)n * 128);

    float acc[64];
    #pragma unroll
    for (int o = 0; o < 64; ++o) acc[o] = 0.f;

    float lsum = 0.f;
    #pragma unroll
    for (int g = 0; g < 8; ++g) {
        uint4 uh = zr[g];
        uint4 ul = zr[8 + g];
        float4 qa = qr[2*g], qb = qr[2*g + 1];
        float zv[8];
        zv[0] = bf2f((u16)(uh.x & 0xFFFF)) + bf2f((u16)(ul.x & 0xFFFF));
        zv[1] = bf2f((u16)(uh.x >> 16))    + bf2f((u16)(ul.x >> 16));
        zv[2] = bf2f((u16)(uh.y & 0xFFFF)) + bf2f((u16)(ul.y & 0xFFFF));
        zv[3] = bf2f((u16)(uh.y >> 16))    + bf2f((u16)(ul.y >> 16));
        zv[4] = bf2f((u16)(uh.z & 0xFFFF)) + bf2f((u16)(ul.z & 0xFFFF));
        zv[5] = bf2f((u16)(uh.z >> 16))    + bf2f((u16)(ul.z >> 16));
        zv[6] = bf2f((u16)(uh.w & 0xFFFF)) + bf2f((u16)(ul.w & 0xFFFF));
        zv[7] = bf2f((u16)(uh.w >> 16))    + bf2f((u16)(ul.w >> 16));
        float qv[8] = {qa.x, qa.y, qa.z, qa.w, qb.x, qb.y, qb.z, qb.w};
        #pragma unroll
        for (int i = 0; i < 8; ++i) {
            float dd = zv[i] - qv[i];
            lsum += dd * dd;
            const int c = g * 8 + i;
            #pragma unroll
            for (int og = 0; og < 16; ++og) {
                float4 w4 = *(const float4*)(wt + c * 64 + og * 4);
                acc[og*4+0] = fmaf(qv[i], w4.x, acc[og*4+0]);
                acc[og*4+1] = fmaf(qv[i], w4.y, acc[og*4+1]);
                acc[og*4+2] = fmaf(qv[i], w4.z, acc[og*4+2]);
                acc[og*4+3] = fmaf(qv[i], w4.w, acc[og*4+3]);
            }
        }
    }

    float* op = out + (size_t)b * (64 * HW) + hw;
    #pragma unroll
    for (int o = 0; o < 64; ++o)
        op[(size_t)o * HW] = acc[o] + bls[o];

    #pragma unroll
    for (int off = 32; off > 0; off >>= 1) lsum += __shfl_down(lsum, off, 64);
    if ((t & 63) == 0) red[t >> 6] = lsum;
    __syncthreads();
    if (t == 0) lossp[blockIdx.x] = red[0] + red[1] + red[2] + red[3];
}

// ---------------------------------------------------------------------------
__global__ void lossred_kernel(const float* __restrict__ lossp, float* __restrict__ loss_out)
{
    __shared__ double sd[128];
    const int t = threadIdx.x;
    sd[t] = (double)lossp[t];
    __syncthreads();
    for (int off = 64; off > 0; off >>= 1) {
        if (t < off) sd[t] += sd[t + off];
        __syncthreads();
    }
    if (t == 0)
        loss_out[0] = (float)(1.25 * sd[0] / (double)((size_t)NTOK * 64));
}

// ---------------------------------------------------------------------------
extern "C" void kernel_launch(void* const* d_in, const int* in_sizes, int n_in,
                              void* d_out, int out_size, void* d_ws, size_t ws_size,
                              hipStream_t stream)
{
    const float* z      = (const float*)d_in[0];
    const float* pre_w  = (const float*)d_in[1];
    const float* pre_b  = (const float*)d_in[2];
    const float* emb    = (const float*)d_in[3];
    const float* post_w = (const float*)d_in[4];
    const float* post_b = (const float*)d_in[5];
    float* outp = (float*)d_out;

    // workspace layout (~10.6 MB)
    u16*   zq       = (u16*)d_ws;                          // N*128 u16 = 8 MB
    float* zz       = (float*)(zq + (size_t)NTOK * 128);   // 128 KB
    float* ee       = zz + NTOK;                           // 32 KB
    u16*   embq     = (u16*)(ee + KCB);                    // K*128 u16 = 2 MB
    uint*  bestidx  = (uint*)(embq + (size_t)KCB * 128);   // 128 KB
    int*   flagcnt  = (int*)(bestidx + NTOK);              // 4 B
    int*   flaglist = flagcnt + 1;                         // 128 KB
    float* lossp    = (float*)(flaglist + NTOK);           // 512 B

    embprep_kernel<<<KCB / 256, 256, 0, stream>>>(emb, embq, ee, flagcnt);
    preconv_kernel<<<NTOK / 256, 256, 0, stream>>>(z, pre_w, pre_b, zq, zz);
    dist_kernel<<<NTOK / 128, 256, 0, stream>>>(zq, embq, ee, bestidx, flagcnt, flaglist);
    cleanup_kernel<<<64, 256, 0, stream>>>(zq, zz, emb, ee, flagcnt, flaglist, bestidx);
    gather_kernel<<<NTOK / 256, 256, 0, stream>>>(emb, bestidx, zq, post_w, post_b, outp, lossp);
    lossred_kernel<<<1, 128, 0, stream>>>(lossp, outp + (size_t)NTOK * 64);
}

// Round 3
// 350.923 us; speedup vs baseline: 1.9359x; 1.3789x over previous
//
#include <hip/hip_runtime.h>
#include <stdint.h>

#define HW 4096
#define NTOK 32768
#define KCB 8192
#define MARGIN 0.01f

typedef __bf16 bf16x8 __attribute__((ext_vector_type(8)));
typedef float f32x16 __attribute__((ext_vector_type(16)));
typedef unsigned int uint;
typedef unsigned short u16;
typedef unsigned long long u64;

static __device__ inline u16 f2bf(float f) {
    uint u = __float_as_uint(f);
    return (u16)((u + 0x7FFFu + ((u >> 16) & 1u)) >> 16);   // RNE
}
static __device__ inline float bf2f(u16 h) {
    return __uint_as_float(((uint)h) << 16);
}
// monotone float<->sortable-uint transform (handles negatives)
static __device__ inline uint fsort(float f) {
    uint u = __float_as_uint(f);
    return u ^ ((uint)((int)u >> 31) | 0x80000000u);
}
static __device__ inline float funsort(uint s) {
    uint m = (s & 0x80000000u) ? 0x80000000u : 0xFFFFFFFFu;
    return __uint_as_float(s ^ m);
}

// ---------------------------------------------------------------------------
// embprep: ee[k] = ||emb_k||^2; embq[k] = 128 bf16 (64 hi then 64 lo) in 16B
// columns XOR-swizzled by (k&7) for conflict-free ds_read_b128. Zeroes flagcnt.
// ---------------------------------------------------------------------------
__global__ __launch_bounds__(256) void embprep_kernel(
    const float* __restrict__ emb, u16* __restrict__ embq,
    float* __restrict__ ee, int* __restrict__ flagcnt)
{
    const int k = blockIdx.x * 256 + threadIdx.x;
    const float4* er = (const float4*)(emb + (size_t)k * 64);
    float vals[64]; float s = 0.f;
    #pragma unroll
    for (int j = 0; j < 16; ++j) {
        float4 v = er[j];
        vals[4*j+0] = v.x; vals[4*j+1] = v.y; vals[4*j+2] = v.z; vals[4*j+3] = v.w;
        s += v.x*v.x + v.y*v.y + v.z*v.z + v.w*v.w;
    }
    ee[k] = s;
    u16 hb[64], lb[64];
    #pragma unroll
    for (int c = 0; c < 64; ++c) {
        hb[c] = f2bf(vals[c]);
        lb[c] = f2bf(vals[c] - bf2f(hb[c]));
    }
    uint4* out = (uint4*)(embq + (size_t)k * 128);
    const int sw = k & 7;
    #pragma unroll
    for (int cl = 0; cl < 8; ++cl) {           // hi columns
        uint4 u;
        u.x = (uint)hb[cl*8+0] | ((uint)hb[cl*8+1] << 16);
        u.y = (uint)hb[cl*8+2] | ((uint)hb[cl*8+3] << 16);
        u.z = (uint)hb[cl*8+4] | ((uint)hb[cl*8+5] << 16);
        u.w = (uint)hb[cl*8+6] | ((uint)hb[cl*8+7] << 16);
        out[cl ^ sw] = u;
    }
    #pragma unroll
    for (int cl = 8; cl < 16; ++cl) {          // lo columns
        const int b = (cl - 8) * 8;
        uint4 u;
        u.x = (uint)lb[b+0] | ((uint)lb[b+1] << 16);
        u.y = (uint)lb[b+2] | ((uint)lb[b+3] << 16);
        u.z = (uint)lb[b+4] | ((uint)lb[b+5] << 16);
        u.w = (uint)lb[b+6] | ((uint)lb[b+7] << 16);
        out[cl ^ sw] = u;
    }
    if (k == 0) *flagcnt = 0;
}

// ---------------------------------------------------------------------------
// preconv: ze = z @ pre_w^T + pre_b; emits zz = ||ze||^2 and zq = bf16 hi/lo.
// ---------------------------------------------------------------------------
__global__ __launch_bounds__(256) void preconv_kernel(
    const float* __restrict__ z, const float* __restrict__ pre_w,
    const float* __restrict__ pre_b, u16* __restrict__ zq, float* __restrict__ zz)
{
    __shared__ __attribute__((aligned(16))) float wt[64 * 64];
    __shared__ float bls[64];
    const int t = threadIdx.x;
    for (int i = t; i < 64 * 64; i += 256) {
        int o = i >> 6, c = i & 63;
        wt[c * 64 + o] = pre_w[i];
    }
    if (t < 64) bls[t] = pre_b[t];
    __syncthreads();

    const int n  = blockIdx.x * 256 + t;
    const int b  = n >> 12;
    const int hw = n & 4095;
    const float* zp = z + (size_t)b * (64 * HW) + hw;

    float acc[64];
    #pragma unroll
    for (int o = 0; o < 64; ++o) acc[o] = 0.f;

    for (int c = 0; c < 64; ++c) {
        float v = zp[(size_t)c * HW];
        #pragma unroll
        for (int og = 0; og < 16; ++og) {
            float4 w4 = *(const float4*)(wt + c * 64 + og * 4);
            acc[og*4+0] = fmaf(v, w4.x, acc[og*4+0]);
            acc[og*4+1] = fmaf(v, w4.y, acc[og*4+1]);
            acc[og*4+2] = fmaf(v, w4.z, acc[og*4+2]);
            acc[og*4+3] = fmaf(v, w4.w, acc[og*4+3]);
        }
    }

    float s = 0.f;
    #pragma unroll
    for (int o = 0; o < 64; ++o) {
        float v = acc[o] + bls[o];
        acc[o] = v;
        s += v * v;
    }
    zz[n] = s;

    uint uh[32], ul[32];
    #pragma unroll
    for (int j = 0; j < 32; ++j) {
        float v0 = acc[2*j], v1 = acc[2*j+1];
        u16 h0 = f2bf(v0), h1 = f2bf(v1);
        u16 l0 = f2bf(v0 - bf2f(h0)), l1 = f2bf(v1 - bf2f(h1));
        uh[j] = (uint)h0 | ((uint)h1 << 16);
        ul[j] = (uint)l0 | ((uint)l1 << 16);
    }
    uint4* zr = (uint4*)(zq + (size_t)n * 128);
    #pragma unroll
    for (int j = 0; j < 8; ++j) {
        zr[j]     = *(uint4*)&uh[4*j];
        zr[8 + j] = *(uint4*)&ul[4*j];
    }
}

// ---------------------------------------------------------------------------
// dist: split-bf16 MFMA distance + top-2 argmin.
// Block = 128 tokens, 4 waves. Wave (th,ch) covers tokens [th*64, th*64+64) x
// codes [ch*64, ch*64+64) of each 128-code chunk -> each wave reads only
// 16 KB/chunk from LDS (4x less than R2). Double-buffered global_load_lds
// staging. Running top-2 (value,index) per token row in registers; final merge
// via sortable-key LDS tables. Tokens with gap < MARGIN flagged for cleanup.
// ---------------------------------------------------------------------------
__global__ __launch_bounds__(256, 1) void dist_kernel(
    const u16* __restrict__ zq, const u16* __restrict__ embq,
    const float* __restrict__ ee, uint* __restrict__ bestidx,
    int* __restrict__ flagcnt, int* __restrict__ flaglist)
{
    __shared__ __attribute__((aligned(16))) char smem[65536];
    __shared__ u64 gbk[128];

    const int t    = threadIdx.x;
    const int w    = t >> 6;
    const int l    = t & 63;
    const int col  = l & 31;
    const int half = l >> 5;
    const int th   = w >> 1;       // token half
    const int ch   = w & 1;        // code half
    const int tok0 = blockIdx.x * 128;

    // ---- A fragments (whole kernel): tg in {0,1} token subtiles of 32 ----
    bf16x8 ah[2][4], al[2][4];
    #pragma unroll
    for (int tg = 0; tg < 2; ++tg) {
        const u16* zrow = zq + (size_t)(tok0 + th*64 + tg*32 + col) * 128;
        #pragma unroll
        for (int s = 0; s < 4; ++s) {
            ah[tg][s] = *(const bf16x8*)(zrow + s*16 + half*8);
            al[tg][s] = *(const bf16x8*)(zrow + 64 + s*16 + half*8);
        }
    }

    // ---- B LDS offsets (per s, hi/lo, ct) ----
    int boh[4][2], bol[4][2];
    #pragma unroll
    for (int s = 0; s < 4; ++s)
        #pragma unroll
        for (int ct = 0; ct < 2; ++ct) {
            const int nl = ch*64 + ct*32 + col;
            const int sw = nl & 7;
            boh[s][ct] = nl*256 + (((s*2 + half) ^ sw) << 4);
            bol[s][ct] = nl*256 + (((8 + s*2 + half) ^ sw) << 4);
        }

    // running top-2 per token row: q = tg*16 + r
    float bb[32], ss[32]; uint ii[32];
    #pragma unroll
    for (int q = 0; q < 32; ++q) { bb[q] = 3.0e38f; ss[q] = 3.0e38f; ii[q] = 0; }

    // ee prefetch (chunk 0)
    float e0 = ee[ch*64 + col];
    float e1 = ee[ch*64 + 32 + col];

    // stage chunk 0
    {
        const char* g = (const char*)embq;
        #pragma unroll
        for (int i = 0; i < 8; ++i) {
            int off = i * 4096 + t * 16;
            __builtin_amdgcn_global_load_lds(
                (const __attribute__((address_space(1))) void*)(g + off),
                (__attribute__((address_space(3))) void*)(smem + off), 16, 0, 0);
        }
    }

    for (int kt = 0; kt < 64; ++kt) {
        __syncthreads();
        if (kt + 1 < 64) {
            const char* g = (const char*)embq + (size_t)(kt + 1) * 32768;
            char* ld = smem + ((kt + 1) & 1) * 32768;
            #pragma unroll
            for (int i = 0; i < 8; ++i) {
                int off = i * 4096 + t * 16;
                __builtin_amdgcn_global_load_lds(
                    (const __attribute__((address_space(1))) void*)(g + off),
                    (__attribute__((address_space(3))) void*)(ld + off), 16, 0, 0);
            }
        }
        const char* buf = smem + (kt & 1) * 32768;

        float e0n = 0.f, e1n = 0.f;
        if (kt + 1 < 64) {
            e0n = ee[(kt+1)*128 + ch*64 + col];
            e1n = ee[(kt+1)*128 + ch*64 + 32 + col];
        }

        f32x16 a00, a01, a10, a11;
        #pragma unroll
        for (int r = 0; r < 16; ++r) { a00[r]=0.f; a01[r]=0.f; a10[r]=0.f; a11[r]=0.f; }

        #pragma unroll
        for (int s = 0; s < 4; ++s) {
            bf16x8 bh0 = *(const bf16x8*)(buf + boh[s][0]);
            bf16x8 bh1 = *(const bf16x8*)(buf + boh[s][1]);
            bf16x8 bl0 = *(const bf16x8*)(buf + bol[s][0]);
            bf16x8 bl1 = *(const bf16x8*)(buf + bol[s][1]);
            a00 = __builtin_amdgcn_mfma_f32_32x32x16_bf16(ah[0][s], bh0, a00, 0, 0, 0);
            a01 = __builtin_amdgcn_mfma_f32_32x32x16_bf16(ah[0][s], bh1, a01, 0, 0, 0);
            a10 = __builtin_amdgcn_mfma_f32_32x32x16_bf16(ah[1][s], bh0, a10, 0, 0, 0);
            a11 = __builtin_amdgcn_mfma_f32_32x32x16_bf16(ah[1][s], bh1, a11, 0, 0, 0);
            a00 = __builtin_amdgcn_mfma_f32_32x32x16_bf16(ah[0][s], bl0, a00, 0, 0, 0);
            a01 = __builtin_amdgcn_mfma_f32_32x32x16_bf16(ah[0][s], bl1, a01, 0, 0, 0);
            a10 = __builtin_amdgcn_mfma_f32_32x32x16_bf16(ah[1][s], bl0, a10, 0, 0, 0);
            a11 = __builtin_amdgcn_mfma_f32_32x32x16_bf16(ah[1][s], bl1, a11, 0, 0, 0);
            a00 = __builtin_amdgcn_mfma_f32_32x32x16_bf16(al[0][s], bh0, a00, 0, 0, 0);
            a01 = __builtin_amdgcn_mfma_f32_32x32x16_bf16(al[0][s], bh1, a01, 0, 0, 0);
            a10 = __builtin_amdgcn_mfma_f32_32x32x16_bf16(al[1][s], bh0, a10, 0, 0, 0);
            a11 = __builtin_amdgcn_mfma_f32_32x32x16_bf16(al[1][s], bh1, a11, 0, 0, 0);
        }

        // epilogue: merge ct pair, then update running top-2
        const uint c0 = (uint)(kt*128 + ch*64 + col);
        #pragma unroll
        for (int tg = 0; tg < 2; ++tg) {
            #pragma unroll
            for (int r = 0; r < 16; ++r) {
                float d0 = fmaf(-2.f, (tg ? a10[r] : a00[r]), e0);
                float d1 = fmaf(-2.f, (tg ? a11[r] : a01[r]), e1);
                float lo = fminf(d0, d1);
                float hi = fmaxf(d0, d1);
                uint i01 = (d1 < d0) ? (c0 + 32) : c0;
                const int q = tg*16 + r;
                float nb = fminf(bb[q], lo);
                ss[q] = fminf(fminf(fmaxf(bb[q], lo), hi), ss[q]);
                ii[q] = (lo < bb[q]) ? i01 : ii[q];
                bb[q] = nb;
            }
        }
        e0 = e0n; e1 = e1n;
    }

    // ---- final merge, pass A: best keys ----
    __syncthreads();
    u64* keyt = (u64*)smem;    // [128 tokens][64 slots]
    #pragma unroll
    for (int q = 0; q < 32; ++q) {
        const int tg = q >> 4, r = q & 15;
        const int tl = th*64 + tg*32 + (r & 3) + 8*(r >> 2) + 4*half;
        keyt[tl*64 + ch*32 + col] = ((u64)fsort(bb[q]) << 32) | ii[q];
    }
    __syncthreads();
    if (t < 128) {
        u64 gb = keyt[t*64 + (t & 63)];
        for (int j = 1; j < 64; ++j) {
            u64 v = keyt[t*64 + ((j + t) & 63)];
            if (v < gb) gb = v;
        }
        gbk[t] = gb;
    }
    __syncthreads();
    // ---- pass B: second-best via substitute values ----
    float* svt = (float*)smem;
    #pragma unroll
    for (int q = 0; q < 32; ++q) {
        const int tg = q >> 4, r = q & 15;
        const int tl = th*64 + tg*32 + (r & 3) + 8*(r >> 2) + 4*half;
        u64 mykey = ((u64)fsort(bb[q]) << 32) | ii[q];
        svt[tl*64 + ch*32 + col] = (mykey == gbk[tl]) ? ss[q] : bb[q];
    }
    __syncthreads();
    if (t < 128) {
        float sv = 3.0e38f;
        for (int j = 0; j < 64; ++j)
            sv = fminf(sv, svt[t*64 + ((j + t) & 63)]);
        const u64 g = gbk[t];
        const float bv = funsort((uint)(g >> 32));
        const int tok = tok0 + t;
        bestidx[tok] = (uint)(g & 0xFFFFFFFFull);
        if (sv - bv < MARGIN) {
            int pos = atomicAdd(flagcnt, 1);
            flaglist[pos] = tok;
        }
    }
}

// ---------------------------------------------------------------------------
// cleanup: exact fp32 rescan for flagged tokens. 256 blocks, 1 token per
// block-iteration, 256 threads stride the 8192 codes. Packed-key argmin
// (first-index tiebreak). zz dropped (constant per token -> argmin invariant).
// ---------------------------------------------------------------------------
__global__ __launch_bounds__(256) void cleanup_kernel(
    const u16* __restrict__ zq, const float* __restrict__ emb,
    const float* __restrict__ ee, const int* __restrict__ flagcnt,
    const int* __restrict__ flaglist, uint* __restrict__ bestidx)
{
    __shared__ __attribute__((aligned(16))) float zf[64];
    __shared__ u64 smin;
    const int cnt = *flagcnt;
    const int t = threadIdx.x;

    for (int fi = blockIdx.x; fi < cnt; fi += 256) {
        const int tok = flaglist[fi];
        if (t == 0) smin = ~0ull;
        if (t < 64) {
            const u16* zr = zq + (size_t)tok * 128;
            zf[t] = bf2f(zr[t]) + bf2f(zr[64 + t]);
        }
        __syncthreads();

        u64 loc = ~0ull;
        #pragma unroll 4
        for (int j = 0; j < 32; ++j) {
            const int k = t + j * 256;
            const float4* er = (const float4*)(emb + (size_t)k * 64);
            float d = 0.f;
            #pragma unroll
            for (int jj = 0; jj < 16; ++jj) {
                float4 e = er[jj];
                float4 zv = *(const float4*)&zf[4*jj];
                d = fmaf(e.x, zv.x, fmaf(e.y, zv.y, fmaf(e.z, zv.z, fmaf(e.w, zv.w, d))));
            }
            float dd = fmaf(-2.f, d, ee[k]);
            u64 key = ((u64)fsort(dd) << 32) | (uint)k;
            if (key < loc) loc = key;
        }
        atomicMin(&smin, loc);
        __syncthreads();
        if (t == 0) bestidx[tok] = (uint)(smin & 0xFFFFFFFFull);
        __syncthreads();
    }
}

// ---------------------------------------------------------------------------
// gather: q = emb[idx]; out = q @ post_w^T + post_b; loss partials (ze-q)^2.
// ---------------------------------------------------------------------------
__global__ __launch_bounds__(256) void gather_kernel(
    const float* __restrict__ emb, const uint* __restrict__ bestidx,
    const u16* __restrict__ zq, const float* __restrict__ post_w,
    const float* __restrict__ post_b, float* __restrict__ out,
    float* __restrict__ lossp)
{
    __shared__ __attribute__((aligned(16))) float wt[64 * 64];
    __shared__ float bls[64];
    __shared__ float red[4];
    const int t = threadIdx.x;
    for (int i = t; i < 64 * 64; i += 256) {
        int o = i >> 6, c = i & 63;
        wt[c * 64 + o] = post_w[i];
    }
    if (t < 64) bls[t] = post_b[t];
    __syncthreads();

    const int n  = blockIdx.x * 256 + t;
    const int b  = n >> 12;
    const int hw = n & 4095;
    const int idx = (int)bestidx[n];

    const float4* qr = (const float4*)(emb + (size_t)idx * 64);
    const uint4*  zr = (const uint4*)(zq + (size_t)n * 128);

    float acc[64];
    #pragma unroll
    for (int o = 0; o < 64; ++o) acc[o] = 0.f;

    float lsum = 0.f;
    #pragma unroll
    for (int g = 0; g < 8; ++g) {
        uint4 uh = zr[g];
        uint4 ul = zr[8 + g];
        float4 qa = qr[2*g], qb = qr[2*g + 1];
        float zv[8];
        zv[0] = bf2f((u16)(uh.x & 0xFFFF)) + bf2f((u16)(ul.x & 0xFFFF));
        zv[1] = bf2f((u16)(uh.x >> 16))    + bf2f((u16)(ul.x >> 16));
        zv[2] = bf2f((u16)(uh.y & 0xFFFF)) + bf2f((u16)(ul.y & 0xFFFF));
        zv[3] = bf2f((u16)(uh.y >> 16))    + bf2f((u16)(ul.y >> 16));
        zv[4] = bf2f((u16)(uh.z & 0xFFFF)) + bf2f((u16)(ul.z & 0xFFFF));
        zv[5] = bf2f((u16)(uh.z >> 16))    + bf2f((u16)(ul.z >> 16));
        zv[6] = bf2f((u16)(uh.w & 0xFFFF)) + bf2f((u16)(ul.w & 0xFFFF));
        zv[7] = bf2f((u16)(uh.w >> 16))    + bf2f((u16)(ul.w >> 16));
        float qv[8] = {qa.x, qa.y, qa.z, qa.w, qb.x, qb.y, qb.z, qb.w};
        #pragma unroll
        for (int i = 0; i < 8; ++i) {
            float dd = zv[i] - qv[i];
            lsum += dd * dd;
            const int c = g * 8 + i;
            #pragma unroll
            for (int og = 0; og < 16; ++og) {
                float4 w4 = *(const float4*)(wt + c * 64 + og * 4);
                acc[og*4+0] = fmaf(qv[i], w4.x, acc[og*4+0]);
                acc[og*4+1] = fmaf(qv[i], w4.y, acc[og*4+1]);
                acc[og*4+2] = fmaf(qv[i], w4.z, acc[og*4+2]);
                acc[og*4+3] = fmaf(qv[i], w4.w, acc[og*4+3]);
            }
        }
    }

    float* op = out + (size_t)b * (64 * HW) + hw;
    #pragma unroll
    for (int o = 0; o < 64; ++o)
        op[(size_t)o * HW] = acc[o] + bls[o];

    #pragma unroll
    for (int off = 32; off > 0; off >>= 1) lsum += __shfl_down(lsum, off, 64);
    if ((t & 63) == 0) red[t >> 6] = lsum;
    __syncthreads();
    if (t == 0) lossp[blockIdx.x] = red[0] + red[1] + red[2] + red[3];
}

// ---------------------------------------------------------------------------
__global__ void lossred_kernel(const float* __restrict__ lossp, float* __restrict__ loss_out)
{
    __shared__ double sd[128];
    const int t = threadIdx.x;
    sd[t] = (double)lossp[t];
    __syncthreads();
    for (int off = 64; off > 0; off >>= 1) {
        if (t < off) sd[t] += sd[t + off];
        __syncthreads();
    }
    if (t == 0)
        loss_out[0] = (float)(1.25 * sd[0] / (double)((size_t)NTOK * 64));
}

// ---------------------------------------------------------------------------
extern "C" void kernel_launch(void* const* d_in, const int* in_sizes, int n_in,
                              void* d_out, int out_size, void* d_ws, size_t ws_size,
                              hipStream_t stream)
{
    const float* z      = (const float*)d_in[0];
    const float* pre_w  = (const float*)d_in[1];
    const float* pre_b  = (const float*)d_in[2];
    const float* emb    = (const float*)d_in[3];
    const float* post_w = (const float*)d_in[4];
    const float* post_b = (const float*)d_in[5];
    float* outp = (float*)d_out;

    u16*   zq       = (u16*)d_ws;                          // N*128 u16 = 8 MB
    float* zz       = (float*)(zq + (size_t)NTOK * 128);   // 128 KB
    float* ee       = zz + NTOK;                           // 32 KB
    u16*   embq     = (u16*)(ee + KCB);                    // K*128 u16 = 2 MB
    uint*  bestidx  = (uint*)(embq + (size_t)KCB * 128);   // 128 KB
    int*   flagcnt  = (int*)(bestidx + NTOK);              // 4 B
    int*   flaglist = flagcnt + 1;                         // 128 KB
    float* lossp    = (float*)(flaglist + NTOK);           // 512 B

    embprep_kernel<<<KCB / 256, 256, 0, stream>>>(emb, embq, ee, flagcnt);
    preconv_kernel<<<NTOK / 256, 256, 0, stream>>>(z, pre_w, pre_b, zq, zz);
    dist_kernel<<<NTOK / 128, 256, 0, stream>>>(zq, embq, ee, bestidx, flagcnt, flaglist);
    cleanup_kernel<<<256, 256, 0, stream>>>(zq, emb, ee, flagcnt, flaglist, bestidx);
    gather_kernel<<<NTOK / 256, 256, 0, stream>>>(emb, bestidx, zq, post_w, post_b, outp, lossp);
    lossred_kernel<<<1, 128, 0, stream>>>(lossp, outp + (size_t)NTOK * 64);
}

// Round 4
// 335.052 us; speedup vs baseline: 2.0276x; 1.0474x over previous
//
#include <hip/hip_runtime.h>
#include <stdint.h>

#define HW 4096
#define NTOK 32768
#define KCB 8192
#define MARGIN 0.01f

typedef __bf16 bf16x8 __attribute__((ext_vector_type(8)));
typedef float f32x16 __attribute__((ext_vector_type(16)));
typedef unsigned int uint;
typedef unsigned short u16;
typedef unsigned long long u64;

static __device__ inline u16 f2bf(float f) {
    uint u = __float_as_uint(f);
    return (u16)((u + 0x7FFFu + ((u >> 16) & 1u)) >> 16);   // RNE
}
static __device__ inline float bf2f(u16 h) {
    return __uint_as_float(((uint)h) << 16);
}
// monotone float<->sortable-uint transform (handles negatives)
static __device__ inline uint fsort(float f) {
    uint u = __float_as_uint(f);
    return u ^ ((uint)((int)u >> 31) | 0x80000000u);
}
static __device__ inline float funsort(uint s) {
    uint m = (s & 0x80000000u) ? 0x80000000u : 0xFFFFFFFFu;
    return __uint_as_float(s ^ m);
}

// ---------------------------------------------------------------------------
// embprep: ee[k] = ||emb_k||^2; embq[k] = 128 bf16 (64 hi then 64 lo) in 16B
// columns XOR-swizzled by (k&7) for conflict-free ds_read_b128. Zeroes flagcnt.
// ---------------------------------------------------------------------------
__global__ __launch_bounds__(256) void embprep_kernel(
    const float* __restrict__ emb, u16* __restrict__ embq,
    float* __restrict__ ee, int* __restrict__ flagcnt)
{
    const int k = blockIdx.x * 256 + threadIdx.x;
    const float4* er = (const float4*)(emb + (size_t)k * 64);
    float vals[64]; float s = 0.f;
    #pragma unroll
    for (int j = 0; j < 16; ++j) {
        float4 v = er[j];
        vals[4*j+0] = v.x; vals[4*j+1] = v.y; vals[4*j+2] = v.z; vals[4*j+3] = v.w;
        s += v.x*v.x + v.y*v.y + v.z*v.z + v.w*v.w;
    }
    ee[k] = s;
    u16 hb[64], lb[64];
    #pragma unroll
    for (int c = 0; c < 64; ++c) {
        hb[c] = f2bf(vals[c]);
        lb[c] = f2bf(vals[c] - bf2f(hb[c]));
    }
    uint4* out = (uint4*)(embq + (size_t)k * 128);
    const int sw = k & 7;
    #pragma unroll
    for (int cl = 0; cl < 8; ++cl) {           // hi columns
        uint4 u;
        u.x = (uint)hb[cl*8+0] | ((uint)hb[cl*8+1] << 16);
        u.y = (uint)hb[cl*8+2] | ((uint)hb[cl*8+3] << 16);
        u.z = (uint)hb[cl*8+4] | ((uint)hb[cl*8+5] << 16);
        u.w = (uint)hb[cl*8+6] | ((uint)hb[cl*8+7] << 16);
        out[cl ^ sw] = u;
    }
    #pragma unroll
    for (int cl = 8; cl < 16; ++cl) {          // lo columns
        const int b = (cl - 8) * 8;
        uint4 u;
        u.x = (uint)lb[b+0] | ((uint)lb[b+1] << 16);
        u.y = (uint)lb[b+2] | ((uint)lb[b+3] << 16);
        u.z = (uint)lb[b+4] | ((uint)lb[b+5] << 16);
        u.w = (uint)lb[b+6] | ((uint)lb[b+7] << 16);
        out[cl ^ sw] = u;
    }
    if (k == 0) *flagcnt = 0;
}

// ---------------------------------------------------------------------------
// preconv: ze = z @ pre_w^T + pre_b; emits zz = ||ze||^2 and zq = bf16 hi/lo.
// ---------------------------------------------------------------------------
__global__ __launch_bounds__(256) void preconv_kernel(
    const float* __restrict__ z, const float* __restrict__ pre_w,
    const float* __restrict__ pre_b, u16* __restrict__ zq, float* __restrict__ zz)
{
    __shared__ __attribute__((aligned(16))) float wt[64 * 64];
    __shared__ float bls[64];
    const int t = threadIdx.x;
    for (int i = t; i < 64 * 64; i += 256) {
        int o = i >> 6, c = i & 63;
        wt[c * 64 + o] = pre_w[i];
    }
    if (t < 64) bls[t] = pre_b[t];
    __syncthreads();

    const int n  = blockIdx.x * 256 + t;
    const int b  = n >> 12;
    const int hw = n & 4095;
    const float* zp = z + (size_t)b * (64 * HW) + hw;

    float acc[64];
    #pragma unroll
    for (int o = 0; o < 64; ++o) acc[o] = 0.f;

    for (int c = 0; c < 64; ++c) {
        float v = zp[(size_t)c * HW];
        #pragma unroll
        for (int og = 0; og < 16; ++og) {
            float4 w4 = *(const float4*)(wt + c * 64 + og * 4);
            acc[og*4+0] = fmaf(v, w4.x, acc[og*4+0]);
            acc[og*4+1] = fmaf(v, w4.y, acc[og*4+1]);
            acc[og*4+2] = fmaf(v, w4.z, acc[og*4+2]);
            acc[og*4+3] = fmaf(v, w4.w, acc[og*4+3]);
        }
    }

    float s = 0.f;
    #pragma unroll
    for (int o = 0; o < 64; ++o) {
        float v = acc[o] + bls[o];
        acc[o] = v;
        s += v * v;
    }
    zz[n] = s;

    uint uh[32], ul[32];
    #pragma unroll
    for (int j = 0; j < 32; ++j) {
        float v0 = acc[2*j], v1 = acc[2*j+1];
        u16 h0 = f2bf(v0), h1 = f2bf(v1);
        u16 l0 = f2bf(v0 - bf2f(h0)), l1 = f2bf(v1 - bf2f(h1));
        uh[j] = (uint)h0 | ((uint)h1 << 16);
        ul[j] = (uint)l0 | ((uint)l1 << 16);
    }
    uint4* zr = (uint4*)(zq + (size_t)n * 128);
    #pragma unroll
    for (int j = 0; j < 8; ++j) {
        zr[j]     = *(uint4*)&uh[4*j];
        zr[8 + j] = *(uint4*)&ul[4*j];
    }
}

// ---------------------------------------------------------------------------
// dist: split-bf16 MFMA distance + top-2 argmin, K-SPLIT across blockIdx.y.
// Grid (256, 2): each block does 128 tokens x 4096 codes (32 chunks of 128).
// 512 blocks -> 2 blocks/CU resident (LDS 2x66.5KB = 133 <= 160KB), 2 waves/
// SIMD: one wave's epilogue/LDS/barrier-drain overlaps the other's MFMA.
// Output per (token, half): u64 key (sortable-best<<32 | idx) + second value.
// ---------------------------------------------------------------------------
__global__ __launch_bounds__(256, 2) void dist_kernel(
    const u16* __restrict__ zq, const u16* __restrict__ embq,
    const float* __restrict__ ee, u64* __restrict__ halfkey,
    float* __restrict__ halfsec)
{
    __shared__ __attribute__((aligned(16))) char smem[65536];
    __shared__ u64 gbk[128];

    const int t    = threadIdx.x;
    const int w    = t >> 6;
    const int l    = t & 63;
    const int col  = l & 31;
    const int half = l >> 5;
    const int th   = w >> 1;       // token half
    const int ch   = w & 1;        // code half (within 128-chunk)
    const int tok0 = blockIdx.x * 128;
    const int y    = blockIdx.y;   // K half
    const int kbase = y * (KCB / 2);

    // ---- A fragments (whole kernel) ----
    bf16x8 ah[2][4], al[2][4];
    #pragma unroll
    for (int tg = 0; tg < 2; ++tg) {
        const u16* zrow = zq + (size_t)(tok0 + th*64 + tg*32 + col) * 128;
        #pragma unroll
        for (int s = 0; s < 4; ++s) {
            ah[tg][s] = *(const bf16x8*)(zrow + s*16 + half*8);
            al[tg][s] = *(const bf16x8*)(zrow + 64 + s*16 + half*8);
        }
    }

    // ---- B LDS offsets ----
    int boh[4][2], bol[4][2];
    #pragma unroll
    for (int s = 0; s < 4; ++s)
        #pragma unroll
        for (int ct = 0; ct < 2; ++ct) {
            const int nl = ch*64 + ct*32 + col;
            const int sw = nl & 7;
            boh[s][ct] = nl*256 + (((s*2 + half) ^ sw) << 4);
            bol[s][ct] = nl*256 + (((8 + s*2 + half) ^ sw) << 4);
        }

    float bb[32], ss[32]; uint ii[32];
    #pragma unroll
    for (int q = 0; q < 32; ++q) { bb[q] = 3.0e38f; ss[q] = 3.0e38f; ii[q] = 0; }

    float e0 = ee[kbase + ch*64 + col];
    float e1 = ee[kbase + ch*64 + 32 + col];

    // stage chunk 0
    {
        const char* g = (const char*)embq + (size_t)kbase * 256;
        #pragma unroll
        for (int i = 0; i < 8; ++i) {
            int off = i * 4096 + t * 16;
            __builtin_amdgcn_global_load_lds(
                (const __attribute__((address_space(1))) void*)(g + off),
                (__attribute__((address_space(3))) void*)(smem + off), 16, 0, 0);
        }
    }

    for (int kt = 0; kt < 32; ++kt) {
        __syncthreads();
        if (kt + 1 < 32) {
            const char* g = (const char*)embq + (size_t)kbase * 256 + (size_t)(kt + 1) * 32768;
            char* ld = smem + ((kt + 1) & 1) * 32768;
            #pragma unroll
            for (int i = 0; i < 8; ++i) {
                int off = i * 4096 + t * 16;
                __builtin_amdgcn_global_load_lds(
                    (const __attribute__((address_space(1))) void*)(g + off),
                    (__attribute__((address_space(3))) void*)(ld + off), 16, 0, 0);
            }
        }
        const char* buf = smem + (kt & 1) * 32768;

        float e0n = 0.f, e1n = 0.f;
        if (kt + 1 < 32) {
            e0n = ee[kbase + (kt+1)*128 + ch*64 + col];
            e1n = ee[kbase + (kt+1)*128 + ch*64 + 32 + col];
        }

        f32x16 a00, a01, a10, a11;
        #pragma unroll
        for (int r = 0; r < 16; ++r) { a00[r]=0.f; a01[r]=0.f; a10[r]=0.f; a11[r]=0.f; }

        #pragma unroll
        for (int s = 0; s < 4; ++s) {
            bf16x8 bh0 = *(const bf16x8*)(buf + boh[s][0]);
            bf16x8 bh1 = *(const bf16x8*)(buf + boh[s][1]);
            bf16x8 bl0 = *(const bf16x8*)(buf + bol[s][0]);
            bf16x8 bl1 = *(const bf16x8*)(buf + bol[s][1]);
            a00 = __builtin_amdgcn_mfma_f32_32x32x16_bf16(ah[0][s], bh0, a00, 0, 0, 0);
            a01 = __builtin_amdgcn_mfma_f32_32x32x16_bf16(ah[0][s], bh1, a01, 0, 0, 0);
            a10 = __builtin_amdgcn_mfma_f32_32x32x16_bf16(ah[1][s], bh0, a10, 0, 0, 0);
            a11 = __builtin_amdgcn_mfma_f32_32x32x16_bf16(ah[1][s], bh1, a11, 0, 0, 0);
            a00 = __builtin_amdgcn_mfma_f32_32x32x16_bf16(ah[0][s], bl0, a00, 0, 0, 0);
            a01 = __builtin_amdgcn_mfma_f32_32x32x16_bf16(ah[0][s], bl1, a01, 0, 0, 0);
            a10 = __builtin_amdgcn_mfma_f32_32x32x16_bf16(ah[1][s], bl0, a10, 0, 0, 0);
            a11 = __builtin_amdgcn_mfma_f32_32x32x16_bf16(ah[1][s], bl1, a11, 0, 0, 0);
            a00 = __builtin_amdgcn_mfma_f32_32x32x16_bf16(al[0][s], bh0, a00, 0, 0, 0);
            a01 = __builtin_amdgcn_mfma_f32_32x32x16_bf16(al[0][s], bh1, a01, 0, 0, 0);
            a10 = __builtin_amdgcn_mfma_f32_32x32x16_bf16(al[1][s], bh0, a10, 0, 0, 0);
            a11 = __builtin_amdgcn_mfma_f32_32x32x16_bf16(al[1][s], bh1, a11, 0, 0, 0);
        }

        const uint c0 = (uint)(kbase + kt*128 + ch*64 + col);
        #pragma unroll
        for (int tg = 0; tg < 2; ++tg) {
            #pragma unroll
            for (int r = 0; r < 16; ++r) {
                float d0 = fmaf(-2.f, (tg ? a10[r] : a00[r]), e0);
                float d1 = fmaf(-2.f, (tg ? a11[r] : a01[r]), e1);
                float lo = fminf(d0, d1);
                float hi = fmaxf(d0, d1);
                uint i01 = (d1 < d0) ? (c0 + 32) : c0;
                const int q = tg*16 + r;
                float nb = fminf(bb[q], lo);
                ss[q] = fminf(fminf(fmaxf(bb[q], lo), hi), ss[q]);
                ii[q] = (lo < bb[q]) ? i01 : ii[q];
                bb[q] = nb;
            }
        }
        e0 = e0n; e1 = e1n;
    }

    // ---- final merge, pass A: best keys ----
    __syncthreads();
    u64* keyt = (u64*)smem;    // [128 tokens][64 slots]
    #pragma unroll
    for (int q = 0; q < 32; ++q) {
        const int tg = q >> 4, r = q & 15;
        const int tl = th*64 + tg*32 + (r & 3) + 8*(r >> 2) + 4*half;
        keyt[tl*64 + ch*32 + col] = ((u64)fsort(bb[q]) << 32) | ii[q];
    }
    __syncthreads();
    if (t < 128) {
        u64 gb = keyt[t*64 + (t & 63)];
        for (int j = 1; j < 64; ++j) {
            u64 v = keyt[t*64 + ((j + t) & 63)];
            if (v < gb) gb = v;
        }
        gbk[t] = gb;
    }
    __syncthreads();
    // ---- pass B: second-best via substitute values ----
    float* svt = (float*)smem;
    #pragma unroll
    for (int q = 0; q < 32; ++q) {
        const int tg = q >> 4, r = q & 15;
        const int tl = th*64 + tg*32 + (r & 3) + 8*(r >> 2) + 4*half;
        u64 mykey = ((u64)fsort(bb[q]) << 32) | ii[q];
        svt[tl*64 + ch*32 + col] = (mykey == gbk[tl]) ? ss[q] : bb[q];
    }
    __syncthreads();
    if (t < 128) {
        float sv = 3.0e38f;
        for (int j = 0; j < 64; ++j)
            sv = fminf(sv, svt[t*64 + ((j + t) & 63)]);
        const int tok = tok0 + t;
        halfkey[(size_t)y * NTOK + tok] = gbk[t];
        halfsec[(size_t)y * NTOK + tok] = sv;
    }
}

// ---------------------------------------------------------------------------
// merge: combine the two K-halves per token -> bestidx + near-tie flags.
// ---------------------------------------------------------------------------
__global__ __launch_bounds__(256) void merge_kernel(
    const u64* __restrict__ halfkey, const float* __restrict__ halfsec,
    uint* __restrict__ bestidx, int* __restrict__ flagcnt,
    int* __restrict__ flaglist)
{
    const int n = blockIdx.x * 256 + threadIdx.x;
    const u64 k0 = halfkey[n], k1 = halfkey[NTOK + n];
    const float s0 = halfsec[n], s1 = halfsec[NTOK + n];
    const u64 kb = (k1 < k0) ? k1 : k0;
    const u64 ko = (k1 < k0) ? k0 : k1;
    const float bv = funsort((uint)(kb >> 32));
    const float ov = funsort((uint)(ko >> 32));
    const float sv = fminf(fminf(s0, s1), ov);
    bestidx[n] = (uint)(kb & 0xFFFFFFFFull);
    if (sv - bv < MARGIN) {
        int pos = atomicAdd(flagcnt, 1);
        flaglist[pos] = n;
    }
}

// ---------------------------------------------------------------------------
// cleanup: exact fp32 rescan for flagged tokens. 256 blocks, 1 token per
// block-iteration, 256 threads stride the 8192 codes. Packed-key argmin
// (first-index tiebreak). zz dropped (constant per token -> argmin invariant).
// ---------------------------------------------------------------------------
__global__ __launch_bounds__(256) void cleanup_kernel(
    const u16* __restrict__ zq, const float* __restrict__ emb,
    const float* __restrict__ ee, const int* __restrict__ flagcnt,
    const int* __restrict__ flaglist, uint* __restrict__ bestidx)
{
    __shared__ __attribute__((aligned(16))) float zf[64];
    __shared__ u64 smin;
    const int cnt = *flagcnt;
    const int t = threadIdx.x;

    for (int fi = blockIdx.x; fi < cnt; fi += 256) {
        const int tok = flaglist[fi];
        if (t == 0) smin = ~0ull;
        if (t < 64) {
            const u16* zr = zq + (size_t)tok * 128;
            zf[t] = bf2f(zr[t]) + bf2f(zr[64 + t]);
        }
        __syncthreads();

        u64 loc = ~0ull;
        #pragma unroll 4
        for (int j = 0; j < 32; ++j) {
            const int k = t + j * 256;
            const float4* er = (const float4*)(emb + (size_t)k * 64);
            float d = 0.f;
            #pragma unroll
            for (int jj = 0; jj < 16; ++jj) {
                float4 e = er[jj];
                float4 zv = *(const float4*)&zf[4*jj];
                d = fmaf(e.x, zv.x, fmaf(e.y, zv.y, fmaf(e.z, zv.z, fmaf(e.w, zv.w, d))));
            }
            float dd = fmaf(-2.f, d, ee[k]);
            u64 key = ((u64)fsort(dd) << 32) | (uint)k;
            if (key < loc) loc = key;
        }
        atomicMin(&smin, loc);
        __syncthreads();
        if (t == 0) bestidx[tok] = (uint)(smin & 0xFFFFFFFFull);
        __syncthreads();
    }
}

// ---------------------------------------------------------------------------
// gather: q = emb[idx]; out = q @ post_w^T + post_b; loss partials (ze-q)^2.
// ---------------------------------------------------------------------------
__global__ __launch_bounds__(256) void gather_kernel(
    const float* __restrict__ emb, const uint* __restrict__ bestidx,
    const u16* __restrict__ zq, const float* __restrict__ post_w,
    const float* __restrict__ post_b, float* __restrict__ out,
    float* __restrict__ lossp)
{
    __shared__ __attribute__((aligned(16))) float wt[64 * 64];
    __shared__ float bls[64];
    __shared__ float red[4];
    const int t = threadIdx.x;
    for (int i = t; i < 64 * 64; i += 256) {
        int o = i >> 6, c = i & 63;
        wt[c * 64 + o] = post_w[i];
    }
    if (t < 64) bls[t] = post_b[t];
    __syncthreads();

    const int n  = blockIdx.x * 256 + t;
    const int b  = n >> 12;
    const int hw = n & 4095;
    const int idx = (int)bestidx[n];

    const float4* qr = (const float4*)(emb + (size_t)idx * 64);
    const uint4*  zr = (const uint4*)(zq + (size_t)n * 128);

    float acc[64];
    #pragma unroll
    for (int o = 0; o < 64; ++o) acc[o] = 0.f;

    float lsum = 0.f;
    #pragma unroll
    for (int g = 0; g < 8; ++g) {
        uint4 uh = zr[g];
        uint4 ul = zr[8 + g];
        float4 qa = qr[2*g], qb = qr[2*g + 1];
        float zv[8];
        zv[0] = bf2f((u16)(uh.x & 0xFFFF)) + bf2f((u16)(ul.x & 0xFFFF));
        zv[1] = bf2f((u16)(uh.x >> 16))    + bf2f((u16)(ul.x >> 16));
        zv[2] = bf2f((u16)(uh.y & 0xFFFF)) + bf2f((u16)(ul.y & 0xFFFF));
        zv[3] = bf2f((u16)(uh.y >> 16))    + bf2f((u16)(ul.y >> 16));
        zv[4] = bf2f((u16)(uh.z & 0xFFFF)) + bf2f((u16)(ul.z & 0xFFFF));
        zv[5] = bf2f((u16)(uh.z >> 16))    + bf2f((u16)(ul.z >> 16));
        zv[6] = bf2f((u16)(uh.w & 0xFFFF)) + bf2f((u16)(ul.w & 0xFFFF));
        zv[7] = bf2f((u16)(uh.w >> 16))    + bf2f((u16)(ul.w >> 16));
        float qv[8] = {qa.x, qa.y, qa.z, qa.w, qb.x, qb.y, qb.z, qb.w};
        #pragma unroll
        for (int i = 0; i < 8; ++i) {
            float dd = zv[i] - qv[i];
            lsum += dd * dd;
            const int c = g * 8 + i;
            #pragma unroll
            for (int og = 0; og < 16; ++og) {
                float4 w4 = *(const float4*)(wt + c * 64 + og * 4);
                acc[og*4+0] = fmaf(qv[i], w4.x, acc[og*4+0]);
                acc[og*4+1] = fmaf(qv[i], w4.y, acc[og*4+1]);
                acc[og*4+2] = fmaf(qv[i], w4.z, acc[og*4+2]);
                acc[og*4+3] = fmaf(qv[i], w4.w, acc[og*4+3]);
            }
        }
    }

    float* op = out + (size_t)b * (64 * HW) + hw;
    #pragma unroll
    for (int o = 0; o < 64; ++o)
        op[(size_t)o * HW] = acc[o] + bls[o];

    #pragma unroll
    for (int off = 32; off > 0; off >>= 1) lsum += __shfl_down(lsum, off, 64);
    if ((t & 63) == 0) red[t >> 6] = lsum;
    __syncthreads();
    if (t == 0) lossp[blockIdx.x] = red[0] + red[1] + red[2] + red[3];
}

// ---------------------------------------------------------------------------
__global__ void lossred_kernel(const float* __restrict__ lossp, float* __restrict__ loss_out)
{
    __shared__ double sd[128];
    const int t = threadIdx.x;
    sd[t] = (double)lossp[t];
    __syncthreads();
    for (int off = 64; off > 0; off >>= 1) {
        if (t < off) sd[t] += sd[t + off];
        __syncthreads();
    }
    if (t == 0)
        loss_out[0] = (float)(1.25 * sd[0] / (double)((size_t)NTOK * 64));
}

// ---------------------------------------------------------------------------
extern "C" void kernel_launch(void* const* d_in, const int* in_sizes, int n_in,
                              void* d_out, int out_size, void* d_ws, size_t ws_size,
                              hipStream_t stream)
{
    const float* z      = (const float*)d_in[0];
    const float* pre_w  = (const float*)d_in[1];
    const float* pre_b  = (const float*)d_in[2];
    const float* emb    = (const float*)d_in[3];
    const float* post_w = (const float*)d_in[4];
    const float* post_b = (const float*)d_in[5];
    float* outp = (float*)d_out;

    u16*   zq       = (u16*)d_ws;                          // N*128 u16 = 8 MB
    float* zz       = (float*)(zq + (size_t)NTOK * 128);   // 128 KB
    float* ee       = zz + NTOK;                           // 32 KB
    u16*   embq     = (u16*)(ee + KCB);                    // K*128 u16 = 2 MB
    uint*  bestidx  = (uint*)(embq + (size_t)KCB * 128);   // 128 KB
    int*   flagcnt  = (int*)(bestidx + NTOK);              // 4 B
    int*   flaglist = flagcnt + 1;                         // 128 KB
    float* lossp    = (float*)(flaglist + NTOK);           // 512 B
    u64*   halfkey  = (u64*)(lossp + 128);                 // 2*N u64 = 512 KB
    float* halfsec  = (float*)(halfkey + 2 * (size_t)NTOK);// 2*N f32 = 256 KB

    embprep_kernel<<<KCB / 256, 256, 0, stream>>>(emb, embq, ee, flagcnt);
    preconv_kernel<<<NTOK / 256, 256, 0, stream>>>(z, pre_w, pre_b, zq, zz);
    dist_kernel<<<dim3(NTOK / 128, 2), 256, 0, stream>>>(zq, embq, ee, halfkey, halfsec);
    merge_kernel<<<NTOK / 256, 256, 0, stream>>>(halfkey, halfsec, bestidx, flagcnt, flaglist);
    cleanup_kernel<<<256, 256, 0, stream>>>(zq, emb, ee, flagcnt, flaglist, bestidx);
    gather_kernel<<<NTOK / 256, 256, 0, stream>>>(emb, bestidx, zq, post_w, post_b, outp, lossp);
    lossred_kernel<<<1, 128, 0, stream>>>(lossp, outp + (size_t)NTOK * 64);
}

// Round 5
// 281.028 us; speedup vs baseline: 2.4173x; 1.1922x over previous
//
#include <hip/hip_runtime.h>
#include <stdint.h>

#define HW 4096
#define NTOK 32768
#define KCB 8192
#define YSPLIT 8
#define KCOV (KCB / YSPLIT)      // 1024 codes per block
#define NCHUNK (KCOV / 64)       // 16 chunks of 64 codes
#define MARGIN 0.01f

typedef __bf16 bf16x8 __attribute__((ext_vector_type(8)));
typedef float f32x16 __attribute__((ext_vector_type(16)));
typedef unsigned int uint;
typedef unsigned short u16;
typedef unsigned long long u64;

static __device__ inline u16 f2bf(float f) {
    uint u = __float_as_uint(f);
    return (u16)((u + 0x7FFFu + ((u >> 16) & 1u)) >> 16);   // RNE
}
static __device__ inline float bf2f(u16 h) {
    return __uint_as_float(((uint)h) << 16);
}
static __device__ inline uint fsort(float f) {
    uint u = __float_as_uint(f);
    return u ^ ((uint)((int)u >> 31) | 0x80000000u);
}
static __device__ inline float funsort(uint s) {
    uint m = (s & 0x80000000u) ? 0x80000000u : 0xFFFFFFFFu;
    return __uint_as_float(s ^ m);
}

// ---------------------------------------------------------------------------
// embprep: ee[k] = ||emb_k||^2; embq[k] = 128 bf16 (64 hi then 64 lo) in 16B
// columns XOR-swizzled by (k&7) for conflict-free ds_read_b128. Zeroes flagcnt.
// ---------------------------------------------------------------------------
__global__ __launch_bounds__(256) void embprep_kernel(
    const float* __restrict__ emb, u16* __restrict__ embq,
    float* __restrict__ ee, int* __restrict__ flagcnt)
{
    const int k = blockIdx.x * 256 + threadIdx.x;
    const float4* er = (const float4*)(emb + (size_t)k * 64);
    float vals[64]; float s = 0.f;
    #pragma unroll
    for (int j = 0; j < 16; ++j) {
        float4 v = er[j];
        vals[4*j+0] = v.x; vals[4*j+1] = v.y; vals[4*j+2] = v.z; vals[4*j+3] = v.w;
        s += v.x*v.x + v.y*v.y + v.z*v.z + v.w*v.w;
    }
    ee[k] = s;
    u16 hb[64], lb[64];
    #pragma unroll
    for (int c = 0; c < 64; ++c) {
        hb[c] = f2bf(vals[c]);
        lb[c] = f2bf(vals[c] - bf2f(hb[c]));
    }
    uint4* out = (uint4*)(embq + (size_t)k * 128);
    const int sw = k & 7;
    #pragma unroll
    for (int cl = 0; cl < 8; ++cl) {
        uint4 u;
        u.x = (uint)hb[cl*8+0] | ((uint)hb[cl*8+1] << 16);
        u.y = (uint)hb[cl*8+2] | ((uint)hb[cl*8+3] << 16);
        u.z = (uint)hb[cl*8+4] | ((uint)hb[cl*8+5] << 16);
        u.w = (uint)hb[cl*8+6] | ((uint)hb[cl*8+7] << 16);
        out[cl ^ sw] = u;
    }
    #pragma unroll
    for (int cl = 8; cl < 16; ++cl) {
        const int b = (cl - 8) * 8;
        uint4 u;
        u.x = (uint)lb[b+0] | ((uint)lb[b+1] << 16);
        u.y = (uint)lb[b+2] | ((uint)lb[b+3] << 16);
        u.z = (uint)lb[b+4] | ((uint)lb[b+5] << 16);
        u.w = (uint)lb[b+6] | ((uint)lb[b+7] << 16);
        out[cl ^ sw] = u;
    }
    if (k == 0) *flagcnt = 0;
}

// ---------------------------------------------------------------------------
// preconv: ze = z @ pre_w^T + pre_b -> zq (bf16 hi/lo). 64 tokens/block,
// 4 threads/token (16 outputs each); z tile staged c-major in LDS.
// ---------------------------------------------------------------------------
__global__ __launch_bounds__(256) void preconv_kernel(
    const float* __restrict__ z, const float* __restrict__ pre_w,
    const float* __restrict__ pre_b, u16* __restrict__ zq)
{
    __shared__ __attribute__((aligned(16))) float wt[64 * 64];  // wt[c*64+o]
    __shared__ __attribute__((aligned(16))) float zt[64 * 64];  // zt[c*64+tok]
    __shared__ float bls[64];
    const int t = threadIdx.x;
    const int tok0 = blockIdx.x * 64;
    const int b    = tok0 >> 12;
    const int hw0  = tok0 & 4095;

    for (int i = t; i < 64 * 64; i += 256) {
        int o = i >> 6, c = i & 63;
        wt[c * 64 + o] = pre_w[i];
    }
    if (t < 64) bls[t] = pre_b[t];
    {
        const int tl = t & 63;
        #pragma unroll
        for (int rr = 0; rr < 16; ++rr) {
            const int c = (t >> 6) + rr * 4;
            zt[c * 64 + tl] = z[(size_t)b * (64 * HW) + (size_t)c * HW + hw0 + tl];
        }
    }
    __syncthreads();

    const int tok = t >> 2;
    const int og  = t & 3;
    const int n   = tok0 + tok;

    float acc[16];
    #pragma unroll
    for (int j = 0; j < 16; ++j) acc[j] = 0.f;

    for (int c = 0; c < 64; ++c) {
        const float zv = zt[c * 64 + tok];
        #pragma unroll
        for (int g = 0; g < 4; ++g) {
            float4 w4 = *(const float4*)(wt + c * 64 + og * 16 + g * 4);
            acc[g*4+0] = fmaf(zv, w4.x, acc[g*4+0]);
            acc[g*4+1] = fmaf(zv, w4.y, acc[g*4+1]);
            acc[g*4+2] = fmaf(zv, w4.z, acc[g*4+2]);
            acc[g*4+3] = fmaf(zv, w4.w, acc[g*4+3]);
        }
    }
    #pragma unroll
    for (int j = 0; j < 16; ++j) acc[j] += bls[og * 16 + j];

    uint uh[8], ul[8];
    #pragma unroll
    for (int j = 0; j < 8; ++j) {
        float v0 = acc[2*j], v1 = acc[2*j+1];
        u16 h0 = f2bf(v0), h1 = f2bf(v1);
        u16 l0 = f2bf(v0 - bf2f(h0)), l1 = f2bf(v1 - bf2f(h1));
        uh[j] = (uint)h0 | ((uint)h1 << 16);
        ul[j] = (uint)l0 | ((uint)l1 << 16);
    }
    uint4* zh = (uint4*)(zq + (size_t)n * 128 + og * 16);
    uint4* zl = (uint4*)(zq + (size_t)n * 128 + 64 + og * 16);
    zh[0] = *(uint4*)&uh[0]; zh[1] = *(uint4*)&uh[4];
    zl[0] = *(uint4*)&ul[0]; zl[1] = *(uint4*)&ul[4];
}

// ---------------------------------------------------------------------------
// dist: split-bf16 MFMA distance + top-2 argmin.
// Grid (256, 8): block = 128 tokens x 1024 codes (16 chunks of 64).
// 4 waves = 4-way TOKEN split (wave w: tokens w*32..w*32+31, all 64 codes of
// each chunk as 2 ct subtiles). LDS: 2x16KB staging double-buffer, reused as
// the 32KB merge table. Low regs + low LDS -> 3+ waves/SIMD.
// ---------------------------------------------------------------------------
__global__ __launch_bounds__(256, 3) void dist_kernel(
    const u16* __restrict__ zq, const u16* __restrict__ embq,
    const float* __restrict__ ee, u64* __restrict__ halfkey,
    float* __restrict__ halfsec)
{
    __shared__ __attribute__((aligned(16))) char smem[32768];
    __shared__ u64 gbk[128];

    const int t    = threadIdx.x;
    const int w    = t >> 6;
    const int l    = t & 63;
    const int col  = l & 31;
    const int half = l >> 5;
    const int tok0 = blockIdx.x * 128;
    const int y    = blockIdx.y;
    const int kbase = y * KCOV;

    // A fragments: wave's 32 tokens, resident all kernel
    bf16x8 ah[4], al[4];
    {
        const u16* zrow = zq + (size_t)(tok0 + w * 32 + col) * 128;
        #pragma unroll
        for (int s = 0; s < 4; ++s) {
            ah[s] = *(const bf16x8*)(zrow + s*16 + half*8);
            al[s] = *(const bf16x8*)(zrow + 64 + s*16 + half*8);
        }
    }

    // B LDS offsets: row nl=ct*32+col, col cl hi=(s*2+half), lo=8+s*2+half,
    // swizzled by (nl&7)==(col&7)
    const int sw = col & 7;
    int boh[4][2], bol[4][2];
    #pragma unroll
    for (int s = 0; s < 4; ++s)
        #pragma unroll
        for (int ct = 0; ct < 2; ++ct) {
            const int nl = ct * 32 + col;
            boh[s][ct] = nl * 256 + (((s*2 + half) ^ sw) << 4);
            bol[s][ct] = nl * 256 + (((8 + s*2 + half) ^ sw) << 4);
        }

    float bb[16], ss[16]; uint ii[16];
    #pragma unroll
    for (int r = 0; r < 16; ++r) { bb[r] = 3.0e38f; ss[r] = 3.0e38f; ii[r] = 0; }

    float e0 = ee[kbase + col];
    float e1 = ee[kbase + 32 + col];
    uint cb0 = (uint)(kbase + col);
    uint cb1 = cb0 + 32;

    // stage chunk 0 (16 KB: 4 x 4KB rounds)
    {
        const char* g = (const char*)embq + (size_t)kbase * 256;
        #pragma unroll
        for (int i = 0; i < 4; ++i) {
            int off = i * 4096 + t * 16;
            __builtin_amdgcn_global_load_lds(
                (const __attribute__((address_space(1))) void*)(g + off),
                (__attribute__((address_space(3))) void*)(smem + off), 16, 0, 0);
        }
    }

    for (int kt = 0; kt < NCHUNK; ++kt) {
        __syncthreads();
        if (kt + 1 < NCHUNK) {
            const char* g = (const char*)embq + (size_t)kbase * 256 + (size_t)(kt + 1) * 16384;
            char* ld = smem + ((kt + 1) & 1) * 16384;
            #pragma unroll
            for (int i = 0; i < 4; ++i) {
                int off = i * 4096 + t * 16;
                __builtin_amdgcn_global_load_lds(
                    (const __attribute__((address_space(1))) void*)(g + off),
                    (__attribute__((address_space(3))) void*)(ld + off), 16, 0, 0);
            }
        }
        const char* buf = smem + (kt & 1) * 16384;

        float e0n = 0.f, e1n = 0.f;
        if (kt + 1 < NCHUNK) {
            e0n = ee[kbase + (kt+1)*64 + col];
            e1n = ee[kbase + (kt+1)*64 + 32 + col];
        }

        f32x16 a0, a1;
        #pragma unroll
        for (int r = 0; r < 16; ++r) { a0[r] = 0.f; a1[r] = 0.f; }

        #pragma unroll
        for (int s = 0; s < 4; ++s) {
            bf16x8 bh0 = *(const bf16x8*)(buf + boh[s][0]);
            bf16x8 bh1 = *(const bf16x8*)(buf + boh[s][1]);
            bf16x8 bl0 = *(const bf16x8*)(buf + bol[s][0]);
            bf16x8 bl1 = *(const bf16x8*)(buf + bol[s][1]);
            a0 = __builtin_amdgcn_mfma_f32_32x32x16_bf16(ah[s], bh0, a0, 0, 0, 0);
            a1 = __builtin_amdgcn_mfma_f32_32x32x16_bf16(ah[s], bh1, a1, 0, 0, 0);
            a0 = __builtin_amdgcn_mfma_f32_32x32x16_bf16(ah[s], bl0, a0, 0, 0, 0);
            a1 = __builtin_amdgcn_mfma_f32_32x32x16_bf16(ah[s], bl1, a1, 0, 0, 0);
            a0 = __builtin_amdgcn_mfma_f32_32x32x16_bf16(al[s], bh0, a0, 0, 0, 0);
            a1 = __builtin_amdgcn_mfma_f32_32x32x16_bf16(al[s], bh1, a1, 0, 0, 0);
        }

        // epilogue: pair-merge ct0/ct1 then running top-2 per token slot
        #pragma unroll
        for (int r = 0; r < 16; ++r) {
            float d0 = fmaf(-2.f, a0[r], e0);
            float d1 = fmaf(-2.f, a1[r], e1);
            float lo = fminf(d0, d1);
            float hi = fmaxf(d0, d1);
            uint i01 = (d1 < d0) ? cb1 : cb0;
            float m  = fmaxf(bb[r], lo);
            ii[r] = (lo < bb[r]) ? i01 : ii[r];
            bb[r] = fminf(bb[r], lo);
            ss[r] = fminf(fminf(m, hi), ss[r]);
        }
        e0 = e0n; e1 = e1n;
        cb0 += 64; cb1 += 64;
    }

    // ---- merge pass A: best keys. slots per token = 32 (cols) ----
    __syncthreads();
    u64* keyt = (u64*)smem;    // [128 tokens][32 slots] = 32 KB
    #pragma unroll
    for (int r = 0; r < 16; ++r) {
        const int tw = (r & 3) + 8 * (r >> 2) + 4 * half;
        keyt[(w * 32 + tw) * 32 + col] = ((u64)fsort(bb[r]) << 32) | ii[r];
    }
    __syncthreads();
    if (t < 128) {
        u64 gb = keyt[t * 32 + (t & 31)];
        for (int j = 1; j < 32; ++j) {
            u64 v = keyt[t * 32 + ((j + t) & 31)];
            if (v < gb) gb = v;
        }
        gbk[t] = gb;
    }
    __syncthreads();
    // ---- pass B: second-best via substitute values ----
    float* svt = (float*)smem;
    #pragma unroll
    for (int r = 0; r < 16; ++r) {
        const int tw = (r & 3) + 8 * (r >> 2) + 4 * half;
        const int tl = w * 32 + tw;
        u64 mykey = ((u64)fsort(bb[r]) << 32) | ii[r];
        svt[tl * 32 + col] = (mykey == gbk[tl]) ? ss[r] : bb[r];
    }
    __syncthreads();
    if (t < 128) {
        float sv = 3.0e38f;
        for (int j = 0; j < 32; ++j)
            sv = fminf(sv, svt[t * 32 + ((j + t) & 31)]);
        halfkey[(size_t)y * NTOK + tok0 + t] = gbk[t];
        halfsec[(size_t)y * NTOK + tok0 + t] = sv;
    }
}

// ---------------------------------------------------------------------------
// merge: combine the YSPLIT partitions per token -> bestidx + near-tie flags.
// Exact second-best: min(sec of best partition, second-best partition's best).
// ---------------------------------------------------------------------------
__global__ __launch_bounds__(256) void merge_kernel(
    const u64* __restrict__ halfkey, const float* __restrict__ halfsec,
    uint* __restrict__ bestidx, int* __restrict__ flagcnt,
    int* __restrict__ flaglist)
{
    const int n = blockIdx.x * 256 + threadIdx.x;
    u64 m1 = ~0ull, m2 = ~0ull;
    float smin = 3.0e38f;
    #pragma unroll
    for (int y = 0; y < YSPLIT; ++y) {
        u64 k = halfkey[(size_t)y * NTOK + n];
        u64 hi = (k > m1) ? k : m1;
        m1 = (k < m1) ? k : m1;
        m2 = (hi < m2) ? hi : m2;
        smin = fminf(smin, halfsec[(size_t)y * NTOK + n]);
    }
    const float bv = funsort((uint)(m1 >> 32));
    const float sv = fminf(smin, funsort((uint)(m2 >> 32)));
    bestidx[n] = (uint)(m1 & 0xFFFFFFFFull);
    if (sv - bv < MARGIN) {
        int pos = atomicAdd(flagcnt, 1);
        flaglist[pos] = n;
    }
}

// ---------------------------------------------------------------------------
// cleanup: exact fp32 rescan for flagged near-tie tokens.
// ---------------------------------------------------------------------------
__global__ __launch_bounds__(256) void cleanup_kernel(
    const u16* __restrict__ zq, const float* __restrict__ emb,
    const float* __restrict__ ee, const int* __restrict__ flagcnt,
    const int* __restrict__ flaglist, uint* __restrict__ bestidx)
{
    __shared__ __attribute__((aligned(16))) float zf[64];
    __shared__ u64 smin;
    const int cnt = *flagcnt;
    const int t = threadIdx.x;

    for (int fi = blockIdx.x; fi < cnt; fi += 256) {
        const int tok = flaglist[fi];
        if (t == 0) smin = ~0ull;
        if (t < 64) {
            const u16* zr = zq + (size_t)tok * 128;
            zf[t] = bf2f(zr[t]) + bf2f(zr[64 + t]);
        }
        __syncthreads();

        u64 loc = ~0ull;
        #pragma unroll 4
        for (int j = 0; j < 32; ++j) {
            const int k = t + j * 256;
            const float4* er = (const float4*)(emb + (size_t)k * 64);
            float d = 0.f;
            #pragma unroll
            for (int jj = 0; jj < 16; ++jj) {
                float4 e = er[jj];
                float4 zv = *(const float4*)&zf[4*jj];
                d = fmaf(e.x, zv.x, fmaf(e.y, zv.y, fmaf(e.z, zv.z, fmaf(e.w, zv.w, d))));
            }
            float dd = fmaf(-2.f, d, ee[k]);
            u64 key = ((u64)fsort(dd) << 32) | (uint)k;
            if (key < loc) loc = key;
        }
        atomicMin(&smin, loc);
        __syncthreads();
        if (t == 0) bestidx[tok] = (uint)(smin & 0xFFFFFFFFull);
        __syncthreads();
    }
}

// ---------------------------------------------------------------------------
// gather: q = emb[idx]; out = q @ post_w^T + post_b; loss partials (ze-q)^2.
// 64 tokens/block, 4 threads/token; q tile staged c-major in LDS.
// ---------------------------------------------------------------------------
__global__ __launch_bounds__(256) void gather_kernel(
    const float* __restrict__ emb, const uint* __restrict__ bestidx,
    const u16* __restrict__ zq, const float* __restrict__ post_w,
    const float* __restrict__ post_b, float* __restrict__ out,
    float* __restrict__ lossp)
{
    __shared__ __attribute__((aligned(16))) float wt[64 * 64];  // wt[c*64+o]
    __shared__ __attribute__((aligned(16))) float qt[64 * 64];  // qt[c*64+tok]
    __shared__ float bls[64];
    __shared__ int idxs[64];
    __shared__ float red[4];
    const int t = threadIdx.x;
    const int tok0 = blockIdx.x * 64;
    const int b    = tok0 >> 12;
    const int hw0  = tok0 & 4095;

    for (int i = t; i < 64 * 64; i += 256) {
        int o = i >> 6, c = i & 63;
        wt[c * 64 + o] = post_w[i];
    }
    if (t < 64) {
        bls[t] = post_b[t];
        idxs[t] = (int)bestidx[tok0 + t];
    }
    __syncthreads();

    const int tok = t >> 2;
    const int og  = t & 3;
    const int n   = tok0 + tok;

    // stage q rows cooperatively: quad (og) loads 4 float4s of its token's row
    {
        const float4* qr = (const float4*)(emb + (size_t)idxs[tok] * 64);
        #pragma unroll
        for (int p = 0; p < 4; ++p) {
            const int c0 = og * 16 + p * 4;
            float4 v = qr[c0 >> 2];
            qt[(c0+0) * 64 + tok] = v.x;
            qt[(c0+1) * 64 + tok] = v.y;
            qt[(c0+2) * 64 + tok] = v.z;
            qt[(c0+3) * 64 + tok] = v.w;
        }
    }
    __syncthreads();

    float acc[16];
    #pragma unroll
    for (int j = 0; j < 16; ++j) acc[j] = 0.f;

    for (int c = 0; c < 64; ++c) {
        const float qv = qt[c * 64 + tok];
        #pragma unroll
        for (int g = 0; g < 4; ++g) {
            float4 w4 = *(const float4*)(wt + c * 64 + og * 16 + g * 4);
            acc[g*4+0] = fmaf(qv, w4.x, acc[g*4+0]);
            acc[g*4+1] = fmaf(qv, w4.y, acc[g*4+1]);
            acc[g*4+2] = fmaf(qv, w4.z, acc[g*4+2]);
            acc[g*4+3] = fmaf(qv, w4.w, acc[g*4+3]);
        }
    }

    // output
    float* op = out + (size_t)b * (64 * HW) + hw0 + tok;
    #pragma unroll
    for (int j = 0; j < 16; ++j)
        op[(size_t)(og * 16 + j) * HW] = acc[j] + bls[og * 16 + j];

    // loss partial over this thread's 16 channels of its token
    float lsum = 0.f;
    {
        const uint4* zh = (const uint4*)(zq + (size_t)n * 128 + og * 16);
        const uint4* zl = (const uint4*)(zq + (size_t)n * 128 + 64 + og * 16);
        #pragma unroll
        for (int h = 0; h < 2; ++h) {
            uint4 uh = zh[h], ul = zl[h];
            const uint uhv[4] = {uh.x, uh.y, uh.z, uh.w};
            const uint ulv[4] = {ul.x, ul.y, ul.z, ul.w};
            #pragma unroll
            for (int p = 0; p < 4; ++p) {
                const int c = og * 16 + h * 8 + p * 2;
                float z0 = bf2f((u16)(uhv[p] & 0xFFFF)) + bf2f((u16)(ulv[p] & 0xFFFF));
                float z1 = bf2f((u16)(uhv[p] >> 16))    + bf2f((u16)(ulv[p] >> 16));
                float d0 = z0 - qt[c * 64 + tok];
                float d1 = z1 - qt[(c + 1) * 64 + tok];
                lsum += d0 * d0 + d1 * d1;
            }
        }
    }
    #pragma unroll
    for (int off = 32; off > 0; off >>= 1) lsum += __shfl_down(lsum, off, 64);
    if ((t & 63) == 0) red[t >> 6] = lsum;
    __syncthreads();
    if (t == 0) lossp[blockIdx.x] = red[0] + red[1] + red[2] + red[3];
}

// ---------------------------------------------------------------------------
__global__ void lossred_kernel(const float* __restrict__ lossp, float* __restrict__ loss_out)
{
    __shared__ double sd[256];
    const int t = threadIdx.x;
    sd[t] = (double)lossp[t] + (double)lossp[t + 256];
    __syncthreads();
    for (int off = 128; off > 0; off >>= 1) {
        if (t < off) sd[t] += sd[t + off];
        __syncthreads();
    }
    if (t == 0)
        loss_out[0] = (float)(1.25 * sd[0] / (double)((size_t)NTOK * 64));
}

// ---------------------------------------------------------------------------
extern "C" void kernel_launch(void* const* d_in, const int* in_sizes, int n_in,
                              void* d_out, int out_size, void* d_ws, size_t ws_size,
                              hipStream_t stream)
{
    const float* z      = (const float*)d_in[0];
    const float* pre_w  = (const float*)d_in[1];
    const float* pre_b  = (const float*)d_in[2];
    const float* emb    = (const float*)d_in[3];
    const float* post_w = (const float*)d_in[4];
    const float* post_b = (const float*)d_in[5];
    float* outp = (float*)d_out;

    u16*   zq       = (u16*)d_ws;                          // N*128 u16 = 8 MB
    float* ee       = (float*)(zq + (size_t)NTOK * 128);   // 32 KB
    u16*   embq     = (u16*)(ee + KCB);                    // 2 MB
    uint*  bestidx  = (uint*)(embq + (size_t)KCB * 128);   // 128 KB
    int*   flagcnt  = (int*)(bestidx + NTOK);              // 4 B
    int*   flaglist = flagcnt + 1;                         // 128 KB
    float* lossp    = (float*)(flaglist + NTOK);           // 2 KB
    u64*   halfkey  = (u64*)(lossp + 512);                 // Y*N u64 = 2 MB
    float* halfsec  = (float*)(halfkey + (size_t)YSPLIT * NTOK); // 1 MB

    embprep_kernel<<<KCB / 256, 256, 0, stream>>>(emb, embq, ee, flagcnt);
    preconv_kernel<<<NTOK / 64, 256, 0, stream>>>(z, pre_w, pre_b, zq);
    dist_kernel<<<dim3(NTOK / 128, YSPLIT), 256, 0, stream>>>(zq, embq, ee, halfkey, halfsec);
    merge_kernel<<<NTOK / 256, 256, 0, stream>>>(halfkey, halfsec, bestidx, flagcnt, flaglist);
    cleanup_kernel<<<256, 256, 0, stream>>>(zq, emb, ee, flagcnt, flaglist, bestidx);
    gather_kernel<<<NTOK / 64, 256, 0, stream>>>(emb, bestidx, zq, post_w, post_b, outp, lossp);
    lossred_kernel<<<1, 256, 0, stream>>>(lossp, outp + (size_t)NTOK * 64);
}

// Round 6
// 237.432 us; speedup vs baseline: 2.8612x; 1.1836x over previous
//
#include <hip/hip_runtime.h>
#include <stdint.h>

#define HW 4096
#define NTOK 32768
#define KCB 8192
#define YSPLIT 8
#define KCOV (KCB / YSPLIT)      // 1024 codes per block
#define NCHUNK (KCOV / 64)       // 16 chunks of 64 codes
#define MARGIN 0.01f

typedef __bf16 bf16x8 __attribute__((ext_vector_type(8)));
typedef float f32x16 __attribute__((ext_vector_type(16)));
typedef unsigned int uint;
typedef unsigned short u16;
typedef unsigned long long u64;

static __device__ inline u16 f2bf(float f) {
    uint u = __float_as_uint(f);
    return (u16)((u + 0x7FFFu + ((u >> 16) & 1u)) >> 16);   // RNE
}
static __device__ inline float bf2f(u16 h) {
    return __uint_as_float(((uint)h) << 16);
}
static __device__ inline uint fsort(float f) {
    uint u = __float_as_uint(f);
    return u ^ ((uint)((int)u >> 31) | 0x80000000u);
}
static __device__ inline float funsort(uint s) {
    uint m = (s & 0x80000000u) ? 0x80000000u : 0xFFFFFFFFu;
    return __uint_as_float(s ^ m);
}

// ---------------------------------------------------------------------------
// embprep: 8 threads/code (256 blocks). ee[k] = ||e||^2 (shfl-8 reduce);
// embq[k] = 128 bf16 of (-2e) as hi/lo 16B columns, XOR-swizzled by (k&7).
// Storing -2e lets dist fold "ee - 2*dot" entirely into the MFMA (C init=ee).
// ---------------------------------------------------------------------------
__global__ __launch_bounds__(256) void embprep_kernel(
    const float* __restrict__ emb, u16* __restrict__ embq,
    float* __restrict__ ee, int* __restrict__ flagcnt)
{
    const int t   = threadIdx.x;
    const int k   = blockIdx.x * 32 + (t >> 3);
    const int sub = t & 7;
    const float4* er = (const float4*)(emb + (size_t)k * 64 + sub * 8);
    float4 v0 = er[0], v1 = er[1];

    float s = v0.x*v0.x + v0.y*v0.y + v0.z*v0.z + v0.w*v0.w
            + v1.x*v1.x + v1.y*v1.y + v1.z*v1.z + v1.w*v1.w;
    s += __shfl_xor(s, 1, 64);
    s += __shfl_xor(s, 2, 64);
    s += __shfl_xor(s, 4, 64);
    if (sub == 0) ee[k] = s;

    float vals[8] = {-2.f*v0.x, -2.f*v0.y, -2.f*v0.z, -2.f*v0.w,
                     -2.f*v1.x, -2.f*v1.y, -2.f*v1.z, -2.f*v1.w};
    u16 hb[8], lb[8];
    #pragma unroll
    for (int c = 0; c < 8; ++c) {
        hb[c] = f2bf(vals[c]);
        lb[c] = f2bf(vals[c] - bf2f(hb[c]));
    }
    uint4 uh, ul;
    uh.x = (uint)hb[0] | ((uint)hb[1] << 16);
    uh.y = (uint)hb[2] | ((uint)hb[3] << 16);
    uh.z = (uint)hb[4] | ((uint)hb[5] << 16);
    uh.w = (uint)hb[6] | ((uint)hb[7] << 16);
    ul.x = (uint)lb[0] | ((uint)lb[1] << 16);
    ul.y = (uint)lb[2] | ((uint)lb[3] << 16);
    ul.z = (uint)lb[4] | ((uint)lb[5] << 16);
    ul.w = (uint)lb[6] | ((uint)lb[7] << 16);

    const int sw = k & 7;
    uint4* out = (uint4*)(embq + (size_t)k * 128);
    out[sub ^ sw]       = uh;   // hi column
    out[(8 + sub) ^ sw] = ul;   // lo column (stays in 8..15 since sw<8)
    if (k == 0 && t == 0) *flagcnt = 0;
}

// ---------------------------------------------------------------------------
// preconv: ze = z @ pre_w^T + pre_b -> zq (bf16 hi/lo). 64 tokens/block,
// 4 threads/token (16 outputs each); z tile staged c-major in LDS.
// ---------------------------------------------------------------------------
__global__ __launch_bounds__(256) void preconv_kernel(
    const float* __restrict__ z, const float* __restrict__ pre_w,
    const float* __restrict__ pre_b, u16* __restrict__ zq)
{
    __shared__ __attribute__((aligned(16))) float wt[64 * 64];  // wt[c*64+o]
    __shared__ __attribute__((aligned(16))) float zt[64 * 64];  // zt[c*64+tok]
    __shared__ float bls[64];
    const int t = threadIdx.x;
    const int tok0 = blockIdx.x * 64;
    const int b    = tok0 >> 12;
    const int hw0  = tok0 & 4095;

    for (int i = t; i < 64 * 64; i += 256) {
        int o = i >> 6, c = i & 63;
        wt[c * 64 + o] = pre_w[i];
    }
    if (t < 64) bls[t] = pre_b[t];
    {
        const int tl = t & 63;
        #pragma unroll
        for (int rr = 0; rr < 16; ++rr) {
            const int c = (t >> 6) + rr * 4;
            zt[c * 64 + tl] = z[(size_t)b * (64 * HW) + (size_t)c * HW + hw0 + tl];
        }
    }
    __syncthreads();

    const int tok = t >> 2;
    const int og  = t & 3;
    const int n   = tok0 + tok;

    float acc[16];
    #pragma unroll
    for (int j = 0; j < 16; ++j) acc[j] = 0.f;

    for (int c = 0; c < 64; ++c) {
        const float zv = zt[c * 64 + tok];
        #pragma unroll
        for (int g = 0; g < 4; ++g) {
            float4 w4 = *(const float4*)(wt + c * 64 + og * 16 + g * 4);
            acc[g*4+0] = fmaf(zv, w4.x, acc[g*4+0]);
            acc[g*4+1] = fmaf(zv, w4.y, acc[g*4+1]);
            acc[g*4+2] = fmaf(zv, w4.z, acc[g*4+2]);
            acc[g*4+3] = fmaf(zv, w4.w, acc[g*4+3]);
        }
    }
    #pragma unroll
    for (int j = 0; j < 16; ++j) acc[j] += bls[og * 16 + j];

    uint uh[8], ul[8];
    #pragma unroll
    for (int j = 0; j < 8; ++j) {
        float v0 = acc[2*j], v1 = acc[2*j+1];
        u16 h0 = f2bf(v0), h1 = f2bf(v1);
        u16 l0 = f2bf(v0 - bf2f(h0)), l1 = f2bf(v1 - bf2f(h1));
        uh[j] = (uint)h0 | ((uint)h1 << 16);
        ul[j] = (uint)l0 | ((uint)l1 << 16);
    }
    uint4* zh = (uint4*)(zq + (size_t)n * 128 + og * 16);
    uint4* zl = (uint4*)(zq + (size_t)n * 128 + 64 + og * 16);
    zh[0] = *(uint4*)&uh[0]; zh[1] = *(uint4*)&uh[4];
    zl[0] = *(uint4*)&ul[0]; zl[1] = *(uint4*)&ul[4];
}

// ---------------------------------------------------------------------------
// dist: split-bf16 MFMA distance + top-2 argmin. Grid (256, 8):
// block = 128 tokens x 1024 codes (16 chunks of 64), 4 waves = 4-way token
// split. B holds -2e, accumulator initialized to ee[col] -> MFMA result IS
// the distance d (no epilogue FLOPs). Top-2 via min3/med3 idiom.
// ---------------------------------------------------------------------------
__global__ __launch_bounds__(256, 3) void dist_kernel(
    const u16* __restrict__ zq, const u16* __restrict__ embq,
    const float* __restrict__ ee, u64* __restrict__ halfkey,
    float* __restrict__ halfsec)
{
    __shared__ __attribute__((aligned(16))) char smem[32768];
    __shared__ u64 gbk[128];

    const int t    = threadIdx.x;
    const int w    = t >> 6;
    const int l    = t & 63;
    const int col  = l & 31;
    const int half = l >> 5;
    const int tok0 = blockIdx.x * 128;
    const int y    = blockIdx.y;
    const int kbase = y * KCOV;

    // A fragments: wave's 32 tokens, resident all kernel
    bf16x8 ah[4], al[4];
    {
        const u16* zrow = zq + (size_t)(tok0 + w * 32 + col) * 128;
        #pragma unroll
        for (int s = 0; s < 4; ++s) {
            ah[s] = *(const bf16x8*)(zrow + s*16 + half*8);
            al[s] = *(const bf16x8*)(zrow + 64 + s*16 + half*8);
        }
    }

    // B LDS offsets: row nl=ct*32+col, hi col cl=s*2+half, lo cl=8+s*2+half
    const int sw = col & 7;
    int boh[4][2], bol[4][2];
    #pragma unroll
    for (int s = 0; s < 4; ++s)
        #pragma unroll
        for (int ct = 0; ct < 2; ++ct) {
            const int nl = ct * 32 + col;
            boh[s][ct] = nl * 256 + (((s*2 + half) ^ sw) << 4);
            bol[s][ct] = nl * 256 + (((8 + s*2 + half) ^ sw) << 4);
        }

    float bb[16], ss[16]; uint ii[16];
    #pragma unroll
    for (int r = 0; r < 16; ++r) { bb[r] = 3.0e38f; ss[r] = 3.0e38f; ii[r] = 0; }

    float e0 = ee[kbase + col];
    float e1 = ee[kbase + 32 + col];
    uint cb0 = (uint)(kbase + col);
    uint cb1 = cb0 + 32;

    // stage chunk 0 (16 KB)
    {
        const char* g = (const char*)embq + (size_t)kbase * 256;
        #pragma unroll
        for (int i = 0; i < 4; ++i) {
            int off = i * 4096 + t * 16;
            __builtin_amdgcn_global_load_lds(
                (const __attribute__((address_space(1))) void*)(g + off),
                (__attribute__((address_space(3))) void*)(smem + off), 16, 0, 0);
        }
    }

    for (int kt = 0; kt < NCHUNK; ++kt) {
        __syncthreads();
        if (kt + 1 < NCHUNK) {
            const char* g = (const char*)embq + (size_t)kbase * 256 + (size_t)(kt + 1) * 16384;
            char* ld = smem + ((kt + 1) & 1) * 16384;
            #pragma unroll
            for (int i = 0; i < 4; ++i) {
                int off = i * 4096 + t * 16;
                __builtin_amdgcn_global_load_lds(
                    (const __attribute__((address_space(1))) void*)(g + off),
                    (__attribute__((address_space(3))) void*)(ld + off), 16, 0, 0);
            }
        }
        const char* buf = smem + (kt & 1) * 16384;

        float e0n = 0.f, e1n = 0.f;
        if (kt + 1 < NCHUNK) {
            e0n = ee[kbase + (kt+1)*64 + col];
            e1n = ee[kbase + (kt+1)*64 + 32 + col];
        }

        // C init = ee[column] (lane-uniform per column) -> acc is d directly
        f32x16 a0, a1;
        #pragma unroll
        for (int r = 0; r < 16; ++r) { a0[r] = e0; a1[r] = e1; }

        #pragma unroll
        for (int s = 0; s < 4; ++s) {
            bf16x8 bh0 = *(const bf16x8*)(buf + boh[s][0]);
            bf16x8 bh1 = *(const bf16x8*)(buf + boh[s][1]);
            bf16x8 bl0 = *(const bf16x8*)(buf + bol[s][0]);
            bf16x8 bl1 = *(const bf16x8*)(buf + bol[s][1]);
            a0 = __builtin_amdgcn_mfma_f32_32x32x16_bf16(ah[s], bh0, a0, 0, 0, 0);
            a1 = __builtin_amdgcn_mfma_f32_32x32x16_bf16(ah[s], bh1, a1, 0, 0, 0);
            a0 = __builtin_amdgcn_mfma_f32_32x32x16_bf16(ah[s], bl0, a0, 0, 0, 0);
            a1 = __builtin_amdgcn_mfma_f32_32x32x16_bf16(ah[s], bl1, a1, 0, 0, 0);
            a0 = __builtin_amdgcn_mfma_f32_32x32x16_bf16(al[s], bh0, a0, 0, 0, 0);
            a1 = __builtin_amdgcn_mfma_f32_32x32x16_bf16(al[s], bh1, a1, 0, 0, 0);
        }

        // top-2 update: bb' = min(bb, min(d0,d1));
        // ss' = min(ss, med3(bb,d0,d1)) [= second-min of {bb,d0,d1}]
        #pragma unroll
        for (int r = 0; r < 16; ++r) {
            float d0 = a0[r], d1 = a1[r];
            float lo = fminf(d0, d1);
            uint i01 = (d1 < d0) ? cb1 : cb0;
            ii[r] = (lo < bb[r]) ? i01 : ii[r];
            ss[r] = fminf(ss[r], __builtin_amdgcn_fmed3f(bb[r], d0, d1));
            bb[r] = fminf(bb[r], lo);
        }
        e0 = e0n; e1 = e1n;
        cb0 += 64; cb1 += 64;
    }

    // ---- merge pass A: best keys ----
    __syncthreads();
    u64* keyt = (u64*)smem;    // [128 tokens][32 slots] = 32 KB
    #pragma unroll
    for (int r = 0; r < 16; ++r) {
        const int tw = (r & 3) + 8 * (r >> 2) + 4 * half;
        keyt[(w * 32 + tw) * 32 + col] = ((u64)fsort(bb[r]) << 32) | ii[r];
    }
    __syncthreads();
    if (t < 128) {
        u64 gb = keyt[t * 32 + (t & 31)];
        for (int j = 1; j < 32; ++j) {
            u64 v = keyt[t * 32 + ((j + t) & 31)];
            if (v < gb) gb = v;
        }
        gbk[t] = gb;
    }
    __syncthreads();
    // ---- pass B: second-best via substitute values ----
    float* svt = (float*)smem;
    #pragma unroll
    for (int r = 0; r < 16; ++r) {
        const int tw = (r & 3) + 8 * (r >> 2) + 4 * half;
        const int tl = w * 32 + tw;
        u64 mykey = ((u64)fsort(bb[r]) << 32) | ii[r];
        svt[tl * 32 + col] = (mykey == gbk[tl]) ? ss[r] : bb[r];
    }
    __syncthreads();
    if (t < 128) {
        float sv = 3.0e38f;
        for (int j = 0; j < 32; ++j)
            sv = fminf(sv, svt[t * 32 + ((j + t) & 31)]);
        halfkey[(size_t)y * NTOK + tok0 + t] = gbk[t];
        halfsec[(size_t)y * NTOK + tok0 + t] = sv;
    }
}

// ---------------------------------------------------------------------------
// merge: combine YSPLIT partitions -> bestkey (u64 packed). Flagged near-tie
// tokens get bestkey = ~0 (cleanup fills the exact min via atomicMin).
// ---------------------------------------------------------------------------
__global__ __launch_bounds__(256) void merge_kernel(
    const u64* __restrict__ halfkey, const float* __restrict__ halfsec,
    u64* __restrict__ bestkey, int* __restrict__ flagcnt,
    int* __restrict__ flaglist)
{
    const int n = blockIdx.x * 256 + threadIdx.x;
    u64 m1 = ~0ull, m2 = ~0ull;
    float smin = 3.0e38f;
    #pragma unroll
    for (int y = 0; y < YSPLIT; ++y) {
        u64 k = halfkey[(size_t)y * NTOK + n];
        u64 hi = (k > m1) ? k : m1;
        m1 = (k < m1) ? k : m1;
        m2 = (hi < m2) ? hi : m2;
        smin = fminf(smin, halfsec[(size_t)y * NTOK + n]);
    }
    const float bv = funsort((uint)(m1 >> 32));
    const float sv = fminf(smin, funsort((uint)(m2 >> 32)));
    const bool flag = (sv - bv < MARGIN);
    bestkey[n] = flag ? ~0ull : m1;
    if (flag) {
        int pos = atomicAdd(flagcnt, 1);
        flaglist[pos] = n;
    }
}

// ---------------------------------------------------------------------------
// cleanup: exact fp32 rescan for flagged tokens, 32 slices/token (256 codes
// each, 1 code/thread). Wave shfl-min + global atomicMin into bestkey.
// ---------------------------------------------------------------------------
__global__ __launch_bounds__(256) void cleanup_kernel(
    const u16* __restrict__ zq, const float* __restrict__ emb,
    const float* __restrict__ ee, const int* __restrict__ flagcnt,
    const int* __restrict__ flaglist, u64* __restrict__ bestkey)
{
    __shared__ __attribute__((aligned(16))) float zf[64];
    __shared__ u64 smin;
    const int cnt = *flagcnt;
    const int t = threadIdx.x;

    for (int job = blockIdx.x; job < cnt * 32; job += 2048) {
        const int fi    = job >> 5;
        const int slice = job & 31;
        const int tok   = flaglist[fi];
        if (t == 0) smin = ~0ull;
        if (t < 64) {
            const u16* zr = zq + (size_t)tok * 128;
            zf[t] = bf2f(zr[t]) + bf2f(zr[64 + t]);
        }
        __syncthreads();

        const int k = slice * 256 + t;
        const float4* er = (const float4*)(emb + (size_t)k * 64);
        float d = 0.f;
        #pragma unroll
        for (int jj = 0; jj < 16; ++jj) {
            float4 e = er[jj];
            float4 zv = *(const float4*)&zf[4*jj];
            d = fmaf(e.x, zv.x, fmaf(e.y, zv.y, fmaf(e.z, zv.z, fmaf(e.w, zv.w, d))));
        }
        float dd = fmaf(-2.f, d, ee[k]);
        u64 key = ((u64)fsort(dd) << 32) | (uint)k;
        #pragma unroll
        for (int off = 32; off > 0; off >>= 1) {
            u64 o = __shfl_down(key, off, 64);
            key = (o < key) ? o : key;
        }
        if ((t & 63) == 0) atomicMin(&smin, key);
        __syncthreads();
        if (t == 0) atomicMin(&bestkey[tok], smin);
        __syncthreads();
    }
}

// ---------------------------------------------------------------------------
// gather: q = emb[idx]; out = q @ post_w^T + post_b; loss partials (ze-q)^2.
// ---------------------------------------------------------------------------
__global__ __launch_bounds__(256) void gather_kernel(
    const float* __restrict__ emb, const u64* __restrict__ bestkey,
    const u16* __restrict__ zq, const float* __restrict__ post_w,
    const float* __restrict__ post_b, float* __restrict__ out,
    float* __restrict__ lossp)
{
    __shared__ __attribute__((aligned(16))) float wt[64 * 64];  // wt[c*64+o]
    __shared__ __attribute__((aligned(16))) float qt[64 * 64];  // qt[c*64+tok]
    __shared__ float bls[64];
    __shared__ int idxs[64];
    __shared__ float red[4];
    const int t = threadIdx.x;
    const int tok0 = blockIdx.x * 64;
    const int b    = tok0 >> 12;
    const int hw0  = tok0 & 4095;

    for (int i = t; i < 64 * 64; i += 256) {
        int o = i >> 6, c = i & 63;
        wt[c * 64 + o] = post_w[i];
    }
    if (t < 64) {
        bls[t] = post_b[t];
        idxs[t] = (int)(bestkey[tok0 + t] & 0xFFFFFFFFull);
    }
    __syncthreads();

    const int tok = t >> 2;
    const int og  = t & 3;
    const int n   = tok0 + tok;

    {
        const float4* qr = (const float4*)(emb + (size_t)idxs[tok] * 64);
        #pragma unroll
        for (int p = 0; p < 4; ++p) {
            const int c0 = og * 16 + p * 4;
            float4 v = qr[c0 >> 2];
            qt[(c0+0) * 64 + tok] = v.x;
            qt[(c0+1) * 64 + tok] = v.y;
            qt[(c0+2) * 64 + tok] = v.z;
            qt[(c0+3) * 64 + tok] = v.w;
        }
    }
    __syncthreads();

    float acc[16];
    #pragma unroll
    for (int j = 0; j < 16; ++j) acc[j] = 0.f;

    for (int c = 0; c < 64; ++c) {
        const float qv = qt[c * 64 + tok];
        #pragma unroll
        for (int g = 0; g < 4; ++g) {
            float4 w4 = *(const float4*)(wt + c * 64 + og * 16 + g * 4);
            acc[g*4+0] = fmaf(qv, w4.x, acc[g*4+0]);
            acc[g*4+1] = fmaf(qv, w4.y, acc[g*4+1]);
            acc[g*4+2] = fmaf(qv, w4.z, acc[g*4+2]);
            acc[g*4+3] = fmaf(qv, w4.w, acc[g*4+3]);
        }
    }

    float* op = out + (size_t)b * (64 * HW) + hw0 + tok;
    #pragma unroll
    for (int j = 0; j < 16; ++j)
        op[(size_t)(og * 16 + j) * HW] = acc[j] + bls[og * 16 + j];

    float lsum = 0.f;
    {
        const uint4* zh = (const uint4*)(zq + (size_t)n * 128 + og * 16);
        const uint4* zl = (const uint4*)(zq + (size_t)n * 128 + 64 + og * 16);
        #pragma unroll
        for (int h = 0; h < 2; ++h) {
            uint4 uh = zh[h], ul = zl[h];
            const uint uhv[4] = {uh.x, uh.y, uh.z, uh.w};
            const uint ulv[4] = {ul.x, ul.y, ul.z, ul.w};
            #pragma unroll
            for (int p = 0; p < 4; ++p) {
                const int c = og * 16 + h * 8 + p * 2;
                float z0 = bf2f((u16)(uhv[p] & 0xFFFF)) + bf2f((u16)(ulv[p] & 0xFFFF));
                float z1 = bf2f((u16)(uhv[p] >> 16))    + bf2f((u16)(ulv[p] >> 16));
                float d0 = z0 - qt[c * 64 + tok];
                float d1 = z1 - qt[(c + 1) * 64 + tok];
                lsum += d0 * d0 + d1 * d1;
            }
        }
    }
    #pragma unroll
    for (int off = 32; off > 0; off >>= 1) lsum += __shfl_down(lsum, off, 64);
    if ((t & 63) == 0) red[t >> 6] = lsum;
    __syncthreads();
    if (t == 0) lossp[blockIdx.x] = red[0] + red[1] + red[2] + red[3];
}

// ---------------------------------------------------------------------------
__global__ void lossred_kernel(const float* __restrict__ lossp, float* __restrict__ loss_out)
{
    __shared__ double sd[256];
    const int t = threadIdx.x;
    sd[t] = (double)lossp[t] + (double)lossp[t + 256];
    __syncthreads();
    for (int off = 128; off > 0; off >>= 1) {
        if (t < off) sd[t] += sd[t + off];
        __syncthreads();
    }
    if (t == 0)
        loss_out[0] = (float)(1.25 * sd[0] / (double)((size_t)NTOK * 64));
}

// ---------------------------------------------------------------------------
extern "C" void kernel_launch(void* const* d_in, const int* in_sizes, int n_in,
                              void* d_out, int out_size, void* d_ws, size_t ws_size,
                              hipStream_t stream)
{
    const float* z      = (const float*)d_in[0];
    const float* pre_w  = (const float*)d_in[1];
    const float* pre_b  = (const float*)d_in[2];
    const float* emb    = (const float*)d_in[3];
    const float* post_w = (const float*)d_in[4];
    const float* post_b = (const float*)d_in[5];
    float* outp = (float*)d_out;

    u16*   zq       = (u16*)d_ws;                          // N*128 u16 = 8 MB
    float* ee       = (float*)(zq + (size_t)NTOK * 128);   // 32 KB
    u16*   embq     = (u16*)(ee + KCB);                    // 2 MB
    u64*   bestkey  = (u64*)(embq + (size_t)KCB * 128);    // 256 KB
    int*   flagcnt  = (int*)(bestkey + NTOK);              // 4 B
    int*   flaglist = flagcnt + 1;                         // 128 KB
    float* lossp    = (float*)(flaglist + NTOK);           // 2 KB
    u64*   halfkey  = (u64*)(lossp + 512);                 // 2 MB
    float* halfsec  = (float*)(halfkey + (size_t)YSPLIT * NTOK); // 1 MB

    embprep_kernel<<<KCB / 32, 256, 0, stream>>>(emb, embq, ee, flagcnt);
    preconv_kernel<<<NTOK / 64, 256, 0, stream>>>(z, pre_w, pre_b, zq);
    dist_kernel<<<dim3(NTOK / 128, YSPLIT), 256, 0, stream>>>(zq, embq, ee, halfkey, halfsec);
    merge_kernel<<<NTOK / 256, 256, 0, stream>>>(halfkey, halfsec, bestkey, flagcnt, flaglist);
    cleanup_kernel<<<2048, 256, 0, stream>>>(zq, emb, ee, flagcnt, flaglist, bestkey);
    gather_kernel<<<NTOK / 64, 256, 0, stream>>>(emb, bestkey, zq, post_w, post_b, outp, lossp);
    lossred_kernel<<<1, 256, 0, stream>>>(lossp, outp + (size_t)NTOK * 64);
}